// Round 15
// baseline (2845.445 us; speedup 1.0000x reference)
//
#include <hip/hip_runtime.h>
#include <hip/hip_bf16.h>

typedef __attribute__((ext_vector_type(8))) short short8;
typedef __attribute__((ext_vector_type(4))) short short4v;
typedef __attribute__((ext_vector_type(4))) float floatx4;

#define MFMA16x32(a, b, c) __builtin_amdgcn_mfma_f32_16x16x32_bf16((a), (b), (c), 0, 0, 0)
#define GLDS(gp, lp) __builtin_amdgcn_global_load_lds( \
    (__attribute__((address_space(1))) unsigned int*)(gp), \
    (__attribute__((address_space(3))) unsigned int*)(lp), 16, 0, 0)

#define NSTEP 50
#define BDIM  256
#define EMBD  1536
#define DETER 2048
#define STOCH 64
#define HID   1024
#define OUTW  2368   // 128 priors + 128 posts + 2048 h + 64 z
#define LNEPS 1e-3f

__device__ __forceinline__ unsigned short f2bf(float f) {
  union { float f; unsigned u; } v; v.f = f;
  unsigned r = v.u + 0x7fffu + ((v.u >> 16) & 1u);   // RNE
  return (unsigned short)(r >> 16);
}
__device__ __forceinline__ float bf2f(unsigned short h) {
  union { unsigned u; float f; } v; v.u = (unsigned)h << 16;
  return v.f;
}
__device__ __forceinline__ float sgm(float x) { return 1.f / (1.f + __expf(-x)); }
__device__ __forceinline__ float elu1(float x) { return x > 0.f ? x : expm1f(x); }

__device__ __forceinline__ void block_sum2(float& s, float& q, float* red, int tid) {
  #pragma unroll
  for (int m = 1; m < 64; m <<= 1) { s += __shfl_xor(s, m, 64); q += __shfl_xor(q, m, 64); }
  int w = tid >> 6;
  if ((tid & 63) == 0) { red[w * 2] = s; red[w * 2 + 1] = q; }
  __syncthreads();
  s = red[0] + red[2] + red[4] + red[6];
  q = red[1] + red[3] + red[5] + red[7];
}

// ---------------- weight prep ----------------
__global__ void k_transpose_bf16(const float* __restrict__ src, int N,
                                 unsigned short* __restrict__ dst, int ldd) {
  __shared__ float tile[32][33];
  int n0 = blockIdx.x * 32, k0 = blockIdx.y * 32;
  for (int i = threadIdx.y; i < 32; i += 8)
    tile[i][threadIdx.x] = src[(size_t)(k0 + i) * N + n0 + threadIdx.x];
  __syncthreads();
  for (int i = threadIdx.y; i < 32; i += 8)
    dst[(size_t)(n0 + i) * ldd + k0 + threadIdx.x] = f2bf(tile[threadIdx.x][i]);
}

// WT gate-interleaved: out row rr: j=(rr/48)*16+(rr&15), g=(rr%48)>>4, src col=g*2048+j
__global__ void k_wt_gate(const float* __restrict__ wi, const float* __restrict__ wh,
                          unsigned short* __restrict__ dst) {
  __shared__ float tile[32][33];
  int r0 = blockIdx.x * 32, k0 = blockIdx.y * 32;
  int rr = r0 + threadIdx.x;
  int j = (rr / 48) * 16 + (rr & 15), g = (rr % 48) >> 4;
  int c = g * 2048 + j;
  for (int i = threadIdx.y; i < 32; i += 8) {
    int k = k0 + i;
    tile[i][threadIdx.x] = (k < 1024) ? wi[(size_t)k * 6144 + c]
                                      : wh[(size_t)(k - 1024) * 6144 + c];
  }
  __syncthreads();
  for (int i = threadIdx.y; i < 32; i += 8)
    dst[(size_t)(r0 + i) * 3072 + k0 + threadIdx.x] = f2bf(tile[threadIdx.x][i]);
}

__global__ void k_cvt_bf16(const float* __restrict__ src, unsigned short* __restrict__ dst, int n) {
  int i = blockIdx.x * blockDim.x + threadIdx.x;
  if (i < n) dst[i] = f2bf(src[i]);
}

__global__ void k_cvt4(const float* __restrict__ src, unsigned short* __restrict__ dst, int n4) {
  int i = blockIdx.x * 256 + threadIdx.x;
  if (i < n4) {
    floatx4 v = ((const floatx4*)src)[i];
    short4v o;
    #pragma unroll
    for (int j = 0; j < 4; j++) o[j] = (short)f2bf(v[j]);
    ((short4v*)dst)[i] = o;
  }
}

__global__ void k_init_state(const float* __restrict__ h0, const unsigned char* __restrict__ reset,
                             float* __restrict__ h_f32, unsigned short* __restrict__ hnb0) {
  int i = blockIdx.x * 256 + threadIdx.x;
  if (i < BDIM * DETER) {
    float m = reset[i >> 11] ? 0.f : 1.f;
    float v = h0[i] * m;
    h_f32[i] = v;
    hnb0[i] = f2bf(v);
  }
}

// ---------------- old-style 64x64 gemm (XAB K=64 f32-A; final prior head) ----------------
template <bool AF32, bool C16>
__global__ __launch_bounds__(256) void k_gemm(
    const void* __restrict__ Ap, long lda,
    const unsigned short* __restrict__ Bt, long ldb,
    const float* __restrict__ bias,
    void* __restrict__ Cp, long ldc, int K) {
  __shared__ __attribute__((aligned(16))) short A_s[64][72];
  __shared__ __attribute__((aligned(16))) short B_s[64][72];
  int n0 = blockIdx.x * 64, m0 = blockIdx.y * 64;
  int tid = threadIdx.x, wave = tid >> 6, lane = tid & 63;
  int srow = tid >> 3, skk = (tid & 7) * 8;
  int fr = lane & 15, fq = lane >> 4;
  int mb = (wave & 1) * 32, nb = (wave >> 1) * 32;
  const unsigned short* a16 = (const unsigned short*)Ap;
  const float* a32 = (const float*)Ap;
  floatx4 acc[2][2] = {};
  for (int k0 = 0; k0 < K; k0 += 64) {
    short8 av0, av1, bv0, bv1;
    if constexpr (AF32) {
      floatx4 f0 = *(const floatx4*)(a32 + (size_t)(m0 + srow) * lda + k0 + skk);
      floatx4 f1 = *(const floatx4*)(a32 + (size_t)(m0 + srow) * lda + k0 + skk + 4);
      floatx4 f2 = *(const floatx4*)(a32 + (size_t)(m0 + srow + 32) * lda + k0 + skk);
      floatx4 f3 = *(const floatx4*)(a32 + (size_t)(m0 + srow + 32) * lda + k0 + skk + 4);
      #pragma unroll
      for (int i = 0; i < 4; i++) {
        av0[i] = (short)f2bf(f0[i]); av0[4 + i] = (short)f2bf(f1[i]);
        av1[i] = (short)f2bf(f2[i]); av1[4 + i] = (short)f2bf(f3[i]);
      }
    } else {
      av0 = *(const short8*)(a16 + (size_t)(m0 + srow) * lda + k0 + skk);
      av1 = *(const short8*)(a16 + (size_t)(m0 + srow + 32) * lda + k0 + skk);
    }
    bv0 = *(const short8*)(Bt + (size_t)(n0 + srow) * ldb + k0 + skk);
    bv1 = *(const short8*)(Bt + (size_t)(n0 + srow + 32) * ldb + k0 + skk);
    __syncthreads();
    *(short8*)&A_s[srow][skk] = av0;
    *(short8*)&A_s[32 + srow][skk] = av1;
    *(short8*)&B_s[srow][skk] = bv0;
    *(short8*)&B_s[32 + srow][skk] = bv1;
    __syncthreads();
    #pragma unroll
    for (int ks = 0; ks < 2; ks++) {
      short8 a0 = *(const short8*)&A_s[mb + fr][ks * 32 + fq * 8];
      short8 a1 = *(const short8*)&A_s[mb + 16 + fr][ks * 32 + fq * 8];
      short8 b0 = *(const short8*)&B_s[nb + fr][ks * 32 + fq * 8];
      short8 b1 = *(const short8*)&B_s[nb + 16 + fr][ks * 32 + fq * 8];
      acc[0][0] = MFMA16x32(a0, b0, acc[0][0]);
      acc[0][1] = MFMA16x32(a0, b1, acc[0][1]);
      acc[1][0] = MFMA16x32(a1, b0, acc[1][0]);
      acc[1][1] = MFMA16x32(a1, b1, acc[1][1]);
    }
  }
  #pragma unroll
  for (int mi = 0; mi < 2; mi++)
    #pragma unroll
    for (int ni = 0; ni < 2; ni++)
      #pragma unroll
      for (int j = 0; j < 4; j++) {
        int row = m0 + mb + mi * 16 + fq * 4 + j;
        int col = n0 + nb + ni * 16 + fr;
        float v = acc[mi][ni][j];
        if (bias) v += bias[col];
        if constexpr (C16) ((unsigned short*)Cp)[(size_t)row * ldc + col] = f2bf(v);
        else               ((float*)Cp)[(size_t)row * ldc + col] = v;
      }
}

// ---------------- 128x64 GLDS+swizzle batch gemm, XCD-chunked, counted-vmcnt, 3 blocks/CU ----------------
// grid = 16 n-tiles x (M/128) m-tiles, XCD-chunked 1-D. LDS 48KB.
template <bool C16>
__global__ __launch_bounds__(256) void k_gemm2(
    const unsigned short* __restrict__ A, long lda,
    const unsigned short* __restrict__ Bt, long ldb,
    const float* __restrict__ bias,
    void* __restrict__ Cp, long ldc, int K) {
  __shared__ __attribute__((aligned(1024))) unsigned short lds[2][192 * 64];
  int per = gridDim.x >> 3;
  int flat = (blockIdx.x & 7) * per + (blockIdx.x >> 3);  // XCD-chunked bijection
  int n0 = (flat & 15) * 64, m0 = (flat >> 4) * 128;
  int tid = threadIdx.x, w = tid >> 6, lane = tid & 63;
  int lr = lane >> 3, ce = ((lane & 7) ^ lr) << 3;
  int fr = lane & 15, fq = lane >> 4;
  int xr = (fr & 7) << 3;
  int wm = (w & 1) * 64, wn = (w >> 1) * 32;
  auto stage = [&](int buf, int k0) {
    #pragma unroll
    for (int q = 0; q < 6; q++) {
      int j = w * 6 + q;
      int rr = j * 8 + lr;
      const unsigned short* src = (rr < 128)
        ? A + (size_t)(m0 + rr) * lda + k0 + ce
        : Bt + (size_t)(n0 + rr - 128) * ldb + k0 + ce;
      GLDS(src, &lds[buf][j * 512]);
    }
  };
  floatx4 acc[4][2] = {};
  int niter = K / 64;
  stage(0, 0); stage(1, 64);
  for (int ks = 0; ks < niter; ks++) {
    int cur = ks & 1;
    if (ks + 1 < niter) asm volatile("s_waitcnt vmcnt(6)" ::: "memory");
    else                asm volatile("s_waitcnt vmcnt(0)" ::: "memory");
    __builtin_amdgcn_s_barrier();
    __builtin_amdgcn_sched_barrier(0);
    const unsigned short* L = lds[cur];
    __builtin_amdgcn_s_setprio(1);
    #pragma unroll
    for (int kh = 0; kh < 2; kh++) {
      int kb = kh * 32 + fq * 8;
      short8 af[4], bf[2];
      #pragma unroll
      for (int i = 0; i < 4; i++)
        af[i] = *(const short8*)&L[((wm + i * 16 + fr) * 64 + kb) ^ xr];
      #pragma unroll
      for (int i = 0; i < 2; i++)
        bf[i] = *(const short8*)&L[((128 + wn + i * 16 + fr) * 64 + kb) ^ xr];
      #pragma unroll
      for (int mi = 0; mi < 4; mi++)
        #pragma unroll
        for (int ni = 0; ni < 2; ni++)
          acc[mi][ni] = MFMA16x32(af[mi], bf[ni], acc[mi][ni]);
    }
    __builtin_amdgcn_s_setprio(0);
    __builtin_amdgcn_sched_barrier(0);
    __builtin_amdgcn_s_barrier();
    if (ks + 2 < niter) stage(cur, (ks + 2) * 64);
  }
  #pragma unroll
  for (int mi = 0; mi < 4; mi++)
    #pragma unroll
    for (int ni = 0; ni < 2; ni++)
      #pragma unroll
      for (int j = 0; j < 4; j++) {
        int row = m0 + wm + mi * 16 + fq * 4 + j;
        int col = n0 + wn + ni * 16 + fr;
        float v = acc[mi][ni][j];
        if (bias) v += bias[col];
        if constexpr (C16) ((unsigned short*)Cp)[(size_t)row * ldc + col] = f2bf(v);
        else               ((float*)Cp)[(size_t)row * ldc + col] = v;
      }
}

// ---------------- per-step k_gru: BM=64 x BN=32, 512 threads (8 waves, kh-split) ----------------
// (round-12 passing version, unchanged)
__global__ __launch_bounds__(512) void k_gru(
    int t, const unsigned short* __restrict__ astk, const unsigned short* __restrict__ hnb_r,
    const unsigned short* __restrict__ wt,
    const float* __restrict__ gbi, const float* __restrict__ gbh,
    const unsigned char* __restrict__ reset,
    float* __restrict__ h_f32, unsigned short* __restrict__ hnb_w,
    unsigned short* __restrict__ hs_bf, float* __restrict__ out) {
  __shared__ __attribute__((aligned(1024))) unsigned short lds[2][192 * 64];
  int raw = blockIdx.x;
  int xcd = raw & 7, ii = raw >> 3;
  int n_t = xcd * 8 + (ii & 7), m_t = ii >> 3;   // n_t 0..63, m_t 0..3
  int m0 = m_t * 64;
  int tid = threadIdx.x, w = tid >> 6, lane = tid & 63;
  int lr = lane >> 3;
  int ce = ((lane & 7) ^ lr) << 3;       // pre-swizzled source col (elem units)
  int fr = lane & 15, fq = lane >> 4;
  int xr = (fr & 7) << 3;                // read-side XOR (short units)
  int wr = w & 1, wc = (w >> 1) & 1, kh = w >> 2;

  auto stage = [&](int buf, int k0) {
    #pragma unroll
    for (int q = 0; q < 3; q++) {
      int j = w * 3 + q;                 // j 0..23 -> rows 0..191
      int rr = j * 8 + lr;
      const unsigned short* src;
      if (rr < 64) {
        src = (k0 < HID) ? astk + (size_t)(m0 + rr) * HID + (k0 + ce)
                         : hnb_r + (size_t)(m0 + rr) * DETER + (k0 - HID + ce);
      } else {
        int wrow = rr - 64;
        if (wrow > 95) wrow = 95;        // pad rows: harmless duplicate load
        src = wt + (size_t)(n_t * 96 + wrow) * 3072 + (k0 + ce);
      }
      GLDS(src, &lds[buf][j * 512]);
    }
  };

  floatx4 acc[2][4] = {};   // [row-half mi][r,u,ic,hc] -- this wave's kh-half only
  stage(0, 0); stage(1, 64);
  for (int ks = 0; ks < 48; ks++) {
    int cur = ks & 1;
    if (ks < 47) asm volatile("s_waitcnt vmcnt(3)" ::: "memory");
    else         asm volatile("s_waitcnt vmcnt(0)" ::: "memory");
    __builtin_amdgcn_s_barrier();
    __builtin_amdgcn_sched_barrier(0);
    const unsigned short* L = lds[cur];
    __builtin_amdgcn_s_setprio(1);
    {
      int kb = kh * 32 + fq * 8;
      short8 a0 = *(const short8*)&L[((wr * 32 + fr) * 64 + kb) ^ xr];
      short8 a1 = *(const short8*)&L[((wr * 32 + 16 + fr) * 64 + kb) ^ xr];
      short8 br = *(const short8*)&L[((64 + wc * 48 + fr) * 64 + kb) ^ xr];
      short8 bu = *(const short8*)&L[((64 + wc * 48 + 16 + fr) * 64 + kb) ^ xr];
      short8 bc = *(const short8*)&L[((64 + wc * 48 + 32 + fr) * 64 + kb) ^ xr];
      acc[0][0] = MFMA16x32(a0, br, acc[0][0]);
      acc[1][0] = MFMA16x32(a1, br, acc[1][0]);
      acc[0][1] = MFMA16x32(a0, bu, acc[0][1]);
      acc[1][1] = MFMA16x32(a1, bu, acc[1][1]);
      if (ks < 16) {
        acc[0][2] = MFMA16x32(a0, bc, acc[0][2]);
        acc[1][2] = MFMA16x32(a1, bc, acc[1][2]);
      } else {
        acc[0][3] = MFMA16x32(a0, bc, acc[0][3]);
        acc[1][3] = MFMA16x32(a1, bc, acc[1][3]);
      }
    }
    __builtin_amdgcn_s_setprio(0);
    __builtin_amdgcn_sched_barrier(0);
    __builtin_amdgcn_s_barrier();
    if (ks + 2 < 48) stage(cur, (ks + 2) * 64);
  }
  // cross-wave kh reduction: waves 4..7 -> waves 0..3 (same wr,wc role)
  __syncthreads();
  float* red = (float*)lds;
  if (w >= 4) {
    int base = ((w - 4) * 64 + lane) * 36;
    #pragma unroll
    for (int mi = 0; mi < 2; mi++)
      #pragma unroll
      for (int g = 0; g < 4; g++)
        *(floatx4*)&red[base + (mi * 4 + g) * 4] = acc[mi][g];
  }
  __syncthreads();
  if (w < 4) {
    int base = (w * 64 + lane) * 36;
    #pragma unroll
    for (int mi = 0; mi < 2; mi++)
      #pragma unroll
      for (int g = 0; g < 4; g++)
        acc[mi][g] += *(const floatx4*)&red[base + (mi * 4 + g) * 4];
    int jc = n_t * 32 + wc * 16 + fr;
    float bir = gbi[jc],        bhr = gbh[jc];
    float biu = gbi[jc + 2048], bhu = gbh[jc + 2048];
    float bic = gbi[jc + 4096], bhc = gbh[jc + 4096];
    #pragma unroll
    for (int mi = 0; mi < 2; mi++)
      #pragma unroll
      for (int j = 0; j < 4; j++) {
        int b = m0 + wr * 32 + mi * 16 + fq * 4 + j;
        float r = sgm(acc[mi][0][j] + bir + bhr);
        float u = sgm(acc[mi][1][j] + biu + bhu);
        float c = tanhf(acc[mi][2][j] + bic + r * (acc[mi][3][j] + bhc));
        size_t hi = (size_t)b * DETER + jc;
        float hold = h_f32[hi];
        float hn = (1.f - u) * c + u * hold;
        out[((size_t)t * BDIM + b) * OUTW + 256 + jc] = hn;
        hs_bf[((size_t)t * BDIM + b) * DETER + jc] = f2bf(hn);
        float mn = (t + 1 < NSTEP && reset[(size_t)(t + 1) * BDIM + b]) ? 0.f : 1.f;
        float hm = hn * mn;
        h_f32[hi] = hm;
        hnb_w[hi] = f2bf(hm);
      }
  }
}

// ---------------- per-step k_ph: 512 threads (8 waves, kh-split), split-K=2 (round-13) ----------------
__global__ __launch_bounds__(512) void k_ph(
    int t, const unsigned short* __restrict__ hsbf, const unsigned short* __restrict__ pht,
    float* __restrict__ x2p) {
  __shared__ __attribute__((aligned(1024))) unsigned short lds[2][128 * 64];
  int raw = blockIdx.x;
  int n_t = raw & 15, m_t = (raw >> 4) & 7, kslc = raw >> 7;
  int m0 = m_t * 32, n0 = n_t * 64, koff = kslc * 1024;
  const unsigned short* hb = hsbf + (size_t)t * BDIM * DETER;
  int tid = threadIdx.x, w = tid >> 6, lane = tid & 63;
  int lr = lane >> 3;
  int ce = ((lane & 7) ^ lr) << 3;
  int fr = lane & 15, fq = lane >> 4;
  int xr = (fr & 7) << 3;
  int wc = w & 3, kh = w >> 2;

  auto stage = [&](int buf, int k0) {
    #pragma unroll
    for (int q = 0; q < 2; q++) {
      int j = w * 2 + q;                 // j 0..15 -> rows 0..127
      int rr = j * 8 + lr;
      const unsigned short* src;
      if (rr < 32) {
        src = hb + (size_t)(m0 + rr) * DETER + koff + k0 + ce;
      } else {
        int brow = rr - 32;
        if (brow > 63) brow = 63;        // pad rows: harmless duplicate load
        src = pht + (size_t)(n0 + brow) * DETER + koff + k0 + ce;
      }
      GLDS(src, &lds[buf][j * 512]);
    }
  };

  floatx4 acc[2] = {};
  stage(0, 0); stage(1, 64);
  for (int ks = 0; ks < 16; ks++) {
    int cur = ks & 1;
    if (ks < 15) asm volatile("s_waitcnt vmcnt(2)" ::: "memory");
    else         asm volatile("s_waitcnt vmcnt(0)" ::: "memory");
    __builtin_amdgcn_s_barrier();
    __builtin_amdgcn_sched_barrier(0);
    const unsigned short* L = lds[cur];
    __builtin_amdgcn_s_setprio(1);
    {
      int kb = kh * 32 + fq * 8;
      short8 a0 = *(const short8*)&L[((fr) * 64 + kb) ^ xr];
      short8 a1 = *(const short8*)&L[((16 + fr) * 64 + kb) ^ xr];
      short8 bw = *(const short8*)&L[((32 + wc * 16 + fr) * 64 + kb) ^ xr];
      acc[0] = MFMA16x32(a0, bw, acc[0]);
      acc[1] = MFMA16x32(a1, bw, acc[1]);
    }
    __builtin_amdgcn_s_setprio(0);
    __builtin_amdgcn_sched_barrier(0);
    __builtin_amdgcn_s_barrier();
    if (ks + 2 < 16) stage(cur, (ks + 2) * 64);
  }
  // kh reduction: waves 4..7 -> 0..3
  __syncthreads();
  float* red = (float*)lds;
  if (kh == 1) {
    int p = w - 4;
    #pragma unroll
    for (int g = 0; g < 2; g++)
      *(floatx4*)&red[((g * 4 + p) * 64 + lane) * 4] = acc[g];
  }
  __syncthreads();
  if (kh == 0) {
    int p = w;
    #pragma unroll
    for (int g = 0; g < 2; g++)
      acc[g] += *(const floatx4*)&red[((g * 4 + p) * 64 + lane) * 4];
    int col = n0 + wc * 16 + fr;
    #pragma unroll
    for (int mi = 0; mi < 2; mi++)
      #pragma unroll
      for (int j = 0; j < 4; j++)
        x2p[(size_t)(kslc * BDIM + m0 + mi * 16 + fq * 4 + j) * HID + col] = acc[mi][j];
  }
}

// ---------------- per-step k_post (zwb bf16) ----------------
__global__ __launch_bounds__(256) void k_post(
    int t, const float* __restrict__ x2p, const float* __restrict__ ph_b,
    const unsigned short* __restrict__ eab,
    const float* __restrict__ pon_g, const float* __restrict__ pon_b,
    const unsigned short* __restrict__ pomb, const float* __restrict__ pom_b,
    const float* __restrict__ noises, const unsigned char* __restrict__ reset,
    const unsigned short* __restrict__ zwb, const unsigned short* __restrict__ xab,
    const float* __restrict__ in_g, const float* __restrict__ in_b,
    float* __restrict__ out, unsigned short* __restrict__ astk) {
  int b = blockIdx.x, tid = threadIdx.x;
  __shared__ float pin[HID];
  __shared__ float red[8];
  __shared__ float post[128];
  __shared__ float zm[64];
  __shared__ float pacc[256];
  int j0 = tid * 4;
  floatx4 x = *(const floatx4*)&x2p[(size_t)b * HID + j0];
  floatx4 x1 = *(const floatx4*)&x2p[(size_t)(BDIM + b) * HID + j0];
  floatx4 bb = *(const floatx4*)&ph_b[j0];
  short4v e4 = *(const short4v*)&eab[((size_t)t * BDIM + b) * HID + j0];
  #pragma unroll
  for (int i = 0; i < 4; i++) x[i] += x1[i] + bb[i] + bf2f((unsigned short)e4[i]);
  float s = x[0] + x[1] + x[2] + x[3];
  float q = x[0]*x[0] + x[1]*x[1] + x[2]*x[2] + x[3]*x[3];
  block_sum2(s, q, red, tid);
  float mean = s * (1.f / HID);
  float rstd = rsqrtf(q * (1.f / HID) - mean * mean + LNEPS);
  floatx4 gg = *(const floatx4*)&pon_g[j0];
  floatx4 ob = *(const floatx4*)&pon_b[j0];
  floatx4 pv;
  #pragma unroll
  for (int i = 0; i < 4; i++) pv[i] = elu1((x[i] - mean) * rstd * gg[i] + ob[i]);
  *(floatx4*)&pin[j0] = pv;
  __syncthreads();
  {
    int col = tid & 127, half = tid >> 7;
    const unsigned short* pb = pomb + (size_t)(half * 512) * 128 + col;
    const float* pi = pin + half * 512;
    float a0 = 0, a1 = 0, a2 = 0, a3 = 0;
    #pragma unroll 8
    for (int k = 0; k < 512; k += 4) {
      a0 += pi[k]     * bf2f(pb[(size_t)k * 128]);
      a1 += pi[k + 1] * bf2f(pb[(size_t)(k + 1) * 128]);
      a2 += pi[k + 2] * bf2f(pb[(size_t)(k + 2) * 128]);
      a3 += pi[k + 3] * bf2f(pb[(size_t)(k + 3) * 128]);
    }
    pacc[tid] = (a0 + a1) + (a2 + a3);
  }
  __syncthreads();
  size_t ro = ((size_t)t * BDIM + b) * OUTW;
  if (tid < 128) {
    float p = pacc[tid] + pacc[tid + 128] + pom_b[tid];
    post[tid] = p;
    out[ro + 128 + tid] = p;
  }
  __syncthreads();
  if (tid < 64) {
    float mn = post[tid], raw = post[64 + tid];
    float std = 2.f * sgm(raw) + 0.1f;
    float z = mn + std * noises[((size_t)t * BDIM + b) * STOCH + tid];
    out[ro + 2304 + tid] = z;
    float mk = (t + 1 < NSTEP && reset[(size_t)(t + 1) * BDIM + b]) ? 0.f : 1.f;
    zm[tid] = z * mk;
  }
  __syncthreads();
  if (t + 1 < NSTEP) {
    short4v xa = *(const short4v*)&xab[((size_t)(t + 1) * BDIM + b) * HID + j0];
    floatx4 xn;
    #pragma unroll
    for (int i = 0; i < 4; i++) xn[i] = bf2f((unsigned short)xa[i]);
    #pragma unroll 8
    for (int k = 0; k < 64; k++) {
      short4v wv4 = *(const short4v*)&zwb[(size_t)k * HID + j0];
      float zk = zm[k];
      #pragma unroll
      for (int i = 0; i < 4; i++) xn[i] += zk * bf2f((unsigned short)wv4[i]);
    }
    float s2 = xn[0] + xn[1] + xn[2] + xn[3];
    float q2 = xn[0]*xn[0] + xn[1]*xn[1] + xn[2]*xn[2] + xn[3]*xn[3];
    block_sum2(s2, q2, red, tid);
    float mean2 = s2 * (1.f / HID);
    float rstd2 = rsqrtf(q2 * (1.f / HID) - mean2 * mean2 + LNEPS);
    floatx4 g2 = *(const floatx4*)&in_g[j0];
    floatx4 b2 = *(const floatx4*)&in_b[j0];
    short4v ov;
    #pragma unroll
    for (int i = 0; i < 4; i++)
      ov[i] = (short)f2bf(elu1((xn[i] - mean2) * rstd2 * g2[i] + b2[i]));
    *(short4v*)&astk[(size_t)b * HID + j0] = ov;
  }
}

// ---------------- t=0 input path ----------------
__global__ __launch_bounds__(256) void k_pre0(
    const float* __restrict__ z0, const unsigned char* __restrict__ reset,
    const float* __restrict__ z_w, const unsigned short* __restrict__ xab,
    const float* __restrict__ in_g, const float* __restrict__ in_b,
    unsigned short* __restrict__ astk) {
  int b = blockIdx.x, tid = threadIdx.x;
  __shared__ float zm[64];
  __shared__ float red[8];
  if (tid < 64) {
    float mk = reset[b] ? 0.f : 1.f;
    zm[tid] = z0[(size_t)b * STOCH + tid] * mk;
  }
  __syncthreads();
  int j0 = tid * 4;
  short4v xa = *(const short4v*)&xab[(size_t)b * HID + j0];
  floatx4 xn;
  #pragma unroll
  for (int i = 0; i < 4; i++) xn[i] = bf2f((unsigned short)xa[i]);
  #pragma unroll 8
  for (int k = 0; k < 64; k++) {
    floatx4 wv = *(const floatx4*)&z_w[(size_t)k * HID + j0];
    xn += zm[k] * wv;
  }
  float s = xn[0] + xn[1] + xn[2] + xn[3];
  float q = xn[0]*xn[0] + xn[1]*xn[1] + xn[2]*xn[2] + xn[3]*xn[3];
  block_sum2(s, q, red, tid);
  float mean = s * (1.f / HID);
  float rstd = rsqrtf(q * (1.f / HID) - mean * mean + LNEPS);
  short4v ov;
  #pragma unroll
  for (int i = 0; i < 4; i++)
    ov[i] = (short)f2bf(elu1((xn[i] - mean) * rstd * in_g[j0 + i] + in_b[j0 + i]));
  *(short4v*)&astk[(size_t)b * HID + j0] = ov;
}

// ---------------- batch LN+ELU (prior path, bf16 in/out) ----------------
__global__ __launch_bounds__(256) void k_ln_elu(
    const unsigned short* __restrict__ X, const float* __restrict__ g, const float* __restrict__ bb,
    unsigned short* __restrict__ Y) {
  int row = blockIdx.x, tid = threadIdx.x;
  __shared__ float red[8];
  int j0 = tid * 4;
  short4v v4 = *(const short4v*)&X[(size_t)row * HID + j0];
  floatx4 v;
  #pragma unroll
  for (int i = 0; i < 4; i++) v[i] = bf2f((unsigned short)v4[i]);
  float s = v[0] + v[1] + v[2] + v[3];
  float q = v[0]*v[0] + v[1]*v[1] + v[2]*v[2] + v[3]*v[3];
  block_sum2(s, q, red, tid);
  float mean = s * (1.f / HID);
  float rstd = rsqrtf(q * (1.f / HID) - mean * mean + LNEPS);
  short4v ov;
  #pragma unroll
  for (int i = 0; i < 4; i++)
    ov[i] = (short)f2bf(elu1((v[i] - mean) * rstd * g[j0 + i] + bb[j0 + i]));
  *(short4v*)&Y[(size_t)row * HID + j0] = ov;
}

extern "C" void kernel_launch(void* const* d_in, const int* in_sizes, int n_in,
                              void* d_out, int out_size, void* d_ws, size_t ws_size,
                              hipStream_t stream) {
  (void)in_sizes; (void)n_in; (void)out_size; (void)ws_size;
  const float* embed  = (const float*)d_in[0];
  const float* action = (const float*)d_in[1];
  const unsigned char* reset = (const unsigned char*)d_in[2];
  const float* h0     = (const float*)d_in[3];
  const float* z0     = (const float*)d_in[4];
  const float* noises = (const float*)d_in[5];
  const float* z_w    = (const float*)d_in[6];
  const float* z_b    = (const float*)d_in[7];
  const float* a_w    = (const float*)d_in[8];
  const float* in_g   = (const float*)d_in[9];
  const float* in_b   = (const float*)d_in[10];
  const float* gru_wi = (const float*)d_in[11];
  const float* gru_wh = (const float*)d_in[12];
  const float* gru_bi = (const float*)d_in[13];
  const float* gru_bh = (const float*)d_in[14];
  const float* ph_w   = (const float*)d_in[15];
  const float* ph_b   = (const float*)d_in[16];
  const float* pe_w   = (const float*)d_in[17];
  const float* pon_g  = (const float*)d_in[18];
  const float* pon_b  = (const float*)d_in[19];
  const float* pom_w  = (const float*)d_in[20];
  const float* pom_b  = (const float*)d_in[21];
  const float* prh_w  = (const float*)d_in[22];
  const float* prh_b  = (const float*)d_in[23];
  const float* prn_g  = (const float*)d_in[24];
  const float* prn_b  = (const float*)d_in[25];
  const float* prm_w  = (const float*)d_in[26];
  const float* prm_b  = (const float*)d_in[27];
  float* out = (float*)d_out;

  // ---- workspace carve (~186 MB) ----
  char* w = (char*)d_ws;
  auto carve = [&](size_t bytes) { char* p = w; w += (bytes + 255) & ~(size_t)255; return p; };
  unsigned short* WT   = (unsigned short*)carve((size_t)6144 * 3072 * 2);
  unsigned short* PHT  = (unsigned short*)carve((size_t)HID * DETER * 2);
  unsigned short* PET  = (unsigned short*)carve((size_t)HID * EMBD * 2);
  unsigned short* AWT  = (unsigned short*)carve((size_t)HID * 64 * 2);
  unsigned short* ZWB  = (unsigned short*)carve((size_t)STOCH * HID * 2);
  unsigned short* POMB = (unsigned short*)carve((size_t)HID * 128 * 2);
  unsigned short* PRHT = (unsigned short*)carve((size_t)HID * DETER * 2);
  unsigned short* PRMT = (unsigned short*)carve((size_t)128 * HID * 2);
  unsigned short* EAB  = (unsigned short*)carve((size_t)NSTEP * BDIM * HID * 2);  // EA bf16
  unsigned short* XPB  = (unsigned short*)carve((size_t)NSTEP * BDIM * HID * 2);  // prior x bf16
  unsigned short* XABP = (unsigned short*)carve((size_t)NSTEP * BDIM * HID * 2);  // XAB, later PRIN
  unsigned short* HSBF = (unsigned short*)carve((size_t)NSTEP * BDIM * DETER * 2);
  unsigned short* ASTK = (unsigned short*)carve((size_t)BDIM * HID * 2);
  unsigned short* HNB0 = (unsigned short*)carve((size_t)BDIM * DETER * 2);
  unsigned short* HNB1 = (unsigned short*)carve((size_t)BDIM * DETER * 2);
  float*          HF32 = (float*)carve((size_t)BDIM * DETER * 4);
  float*          X2P  = (float*)carve((size_t)2 * BDIM * HID * 4);
  unsigned short* EMBB = HSBF;   // overlay: embed-bf16 lives in HSBF until EA gemm done (pre-loop)

  dim3 tb(32, 8);
  // weight prep
  k_wt_gate<<<dim3(192, 96), tb, 0, stream>>>(gru_wi, gru_wh, WT);
  k_transpose_bf16<<<dim3(32, 64), tb, 0, stream>>>(ph_w, 1024, PHT, DETER);
  k_transpose_bf16<<<dim3(32, 48), tb, 0, stream>>>(pe_w, 1024, PET, EMBD);
  k_transpose_bf16<<<dim3(32, 2), tb, 0, stream>>>(a_w, 1024, AWT, 64);
  k_transpose_bf16<<<dim3(32, 64), tb, 0, stream>>>(prh_w, 1024, PRHT, DETER);
  k_transpose_bf16<<<dim3(4, 32), tb, 0, stream>>>(prm_w, 128, PRMT, HID);
  k_cvt_bf16<<<512, 256, 0, stream>>>(pom_w, POMB, HID * 128);
  k_cvt_bf16<<<256, 256, 0, stream>>>(z_w, ZWB, STOCH * HID);
  k_init_state<<<2048, 256, 0, stream>>>(h0, reset, HF32, HNB0);
  // embed -> bf16 (into HSBF overlay)
  k_cvt4<<<(NSTEP * BDIM * EMBD / 4 + 255) / 256, 256, 0, stream>>>(embed, EMBB, NSTEP * BDIM * EMBD / 4);
  // XAB = action @ a_w + z_b (bf16), all steps
  k_gemm<true, true><<<dim3(16, 200), 256, 0, stream>>>(action, 64, AWT, 64, z_b, XABP, HID, 64);
  // EA = embed @ pe_w (bf16), all steps  (128x64 tiles: 16 n x 100 m = 1600 WG)
  k_gemm2<true><<<1600, 256, 0, stream>>>(EMBB, EMBD, PET, EMBD, nullptr, EAB, HID, EMBD);
  // t=0 input path
  k_pre0<<<BDIM, 256, 0, stream>>>(z0, reset, z_w, XABP, in_g, in_b, ASTK);

  for (int t = 0; t < NSTEP; t++) {
    const unsigned short* hr = (t & 1) ? HNB1 : HNB0;
    unsigned short* hw = (t & 1) ? HNB0 : HNB1;
    k_gru<<<256, 512, 0, stream>>>(t, ASTK, hr, WT, gru_bi, gru_bh, reset,
                                   HF32, hw, HSBF, out);
    k_ph<<<256, 512, 0, stream>>>(t, HSBF, PHT, X2P);
    k_post<<<BDIM, 256, 0, stream>>>(t, X2P, ph_b, EAB, pon_g, pon_b, POMB, pom_b,
                                     noises, reset, ZWB, XABP, in_g, in_b, out, ASTK);
  }

  // batch prior: XP = hs @ prh_w + prh_b (bf16); PRIN overlays XABP
  k_gemm2<true><<<1600, 256, 0, stream>>>(HSBF, DETER, PRHT, DETER, prh_b, XPB, HID, DETER);
  k_ln_elu<<<NSTEP * BDIM, 256, 0, stream>>>(XPB, prn_g, prn_b, XABP);
  k_gemm<false, false><<<dim3(2, 200), 256, 0, stream>>>(XABP, HID, PRMT, HID, prm_b, out, OUTW, HID);
}

// Round 16
// 2653.122 us; speedup vs baseline: 1.0725x; 1.0725x over previous
//
#include <hip/hip_runtime.h>
#include <hip/hip_bf16.h>

typedef __attribute__((ext_vector_type(8))) short short8;
typedef __attribute__((ext_vector_type(4))) short short4v;
typedef __attribute__((ext_vector_type(4))) float floatx4;

#define MFMA16x32(a, b, c) __builtin_amdgcn_mfma_f32_16x16x32_bf16((a), (b), (c), 0, 0, 0)
#define GLDS(gp, lp) __builtin_amdgcn_global_load_lds( \
    (__attribute__((address_space(1))) unsigned int*)(gp), \
    (__attribute__((address_space(3))) unsigned int*)(lp), 16, 0, 0)

#define NSTEP 50
#define BDIM  256
#define EMBD  1536
#define DETER 2048
#define STOCH 64
#define HID   1024
#define OUTW  2368   // 128 priors + 128 posts + 2048 h + 64 z
#define LNEPS 1e-3f

__device__ __forceinline__ unsigned short f2bf(float f) {
  union { float f; unsigned u; } v; v.f = f;
  unsigned r = v.u + 0x7fffu + ((v.u >> 16) & 1u);   // RNE
  return (unsigned short)(r >> 16);
}
__device__ __forceinline__ float bf2f(unsigned short h) {
  union { unsigned u; float f; } v; v.u = (unsigned)h << 16;
  return v.f;
}
__device__ __forceinline__ float sgm(float x) { return 1.f / (1.f + __expf(-x)); }
__device__ __forceinline__ float elu1(float x) { return x > 0.f ? x : expm1f(x); }

__device__ __forceinline__ void block_sum2(float& s, float& q, float* red, int tid) {
  #pragma unroll
  for (int m = 1; m < 64; m <<= 1) { s += __shfl_xor(s, m, 64); q += __shfl_xor(q, m, 64); }
  int w = tid >> 6;
  if ((tid & 63) == 0) { red[w * 2] = s; red[w * 2 + 1] = q; }
  __syncthreads();
  s = red[0] + red[2] + red[4] + red[6];
  q = red[1] + red[3] + red[5] + red[7];
}

// ---------------- weight prep ----------------
__global__ void k_transpose_bf16(const float* __restrict__ src, int N,
                                 unsigned short* __restrict__ dst, int ldd) {
  __shared__ float tile[32][33];
  int n0 = blockIdx.x * 32, k0 = blockIdx.y * 32;
  for (int i = threadIdx.y; i < 32; i += 8)
    tile[i][threadIdx.x] = src[(size_t)(k0 + i) * N + n0 + threadIdx.x];
  __syncthreads();
  for (int i = threadIdx.y; i < 32; i += 8)
    dst[(size_t)(n0 + i) * ldd + k0 + threadIdx.x] = f2bf(tile[threadIdx.x][i]);
}

// WT gate-interleaved: out row rr: j=(rr/48)*16+(rr&15), g=(rr%48)>>4, src col=g*2048+j
__global__ void k_wt_gate(const float* __restrict__ wi, const float* __restrict__ wh,
                          unsigned short* __restrict__ dst) {
  __shared__ float tile[32][33];
  int r0 = blockIdx.x * 32, k0 = blockIdx.y * 32;
  int rr = r0 + threadIdx.x;
  int j = (rr / 48) * 16 + (rr & 15), g = (rr % 48) >> 4;
  int c = g * 2048 + j;
  for (int i = threadIdx.y; i < 32; i += 8) {
    int k = k0 + i;
    tile[i][threadIdx.x] = (k < 1024) ? wi[(size_t)k * 6144 + c]
                                      : wh[(size_t)(k - 1024) * 6144 + c];
  }
  __syncthreads();
  for (int i = threadIdx.y; i < 32; i += 8)
    dst[(size_t)(r0 + i) * 3072 + k0 + threadIdx.x] = f2bf(tile[threadIdx.x][i]);
}

__global__ void k_cvt_bf16(const float* __restrict__ src, unsigned short* __restrict__ dst, int n) {
  int i = blockIdx.x * blockDim.x + threadIdx.x;
  if (i < n) dst[i] = f2bf(src[i]);
}

__global__ void k_cvt4(const float* __restrict__ src, unsigned short* __restrict__ dst, int n4) {
  int i = blockIdx.x * 256 + threadIdx.x;
  if (i < n4) {
    floatx4 v = ((const floatx4*)src)[i];
    short4v o;
    #pragma unroll
    for (int j = 0; j < 4; j++) o[j] = (short)f2bf(v[j]);
    ((short4v*)dst)[i] = o;
  }
}

__global__ void k_init_state(const float* __restrict__ h0, const unsigned char* __restrict__ reset,
                             float* __restrict__ h_f32, unsigned short* __restrict__ hnb0) {
  int i = blockIdx.x * 256 + threadIdx.x;
  if (i < BDIM * DETER) {
    float m = reset[i >> 11] ? 0.f : 1.f;
    float v = h0[i] * m;
    h_f32[i] = v;
    hnb0[i] = f2bf(v);
  }
}

// ---------------- old-style 64x64 gemm (XAB K=64 f32-A; final prior head) ----------------
template <bool AF32, bool C16>
__global__ __launch_bounds__(256) void k_gemm(
    const void* __restrict__ Ap, long lda,
    const unsigned short* __restrict__ Bt, long ldb,
    const float* __restrict__ bias,
    void* __restrict__ Cp, long ldc, int K) {
  __shared__ __attribute__((aligned(16))) short A_s[64][72];
  __shared__ __attribute__((aligned(16))) short B_s[64][72];
  int n0 = blockIdx.x * 64, m0 = blockIdx.y * 64;
  int tid = threadIdx.x, wave = tid >> 6, lane = tid & 63;
  int srow = tid >> 3, skk = (tid & 7) * 8;
  int fr = lane & 15, fq = lane >> 4;
  int mb = (wave & 1) * 32, nb = (wave >> 1) * 32;
  const unsigned short* a16 = (const unsigned short*)Ap;
  const float* a32 = (const float*)Ap;
  floatx4 acc[2][2] = {};
  for (int k0 = 0; k0 < K; k0 += 64) {
    short8 av0, av1, bv0, bv1;
    if constexpr (AF32) {
      floatx4 f0 = *(const floatx4*)(a32 + (size_t)(m0 + srow) * lda + k0 + skk);
      floatx4 f1 = *(const floatx4*)(a32 + (size_t)(m0 + srow) * lda + k0 + skk + 4);
      floatx4 f2 = *(const floatx4*)(a32 + (size_t)(m0 + srow + 32) * lda + k0 + skk);
      floatx4 f3 = *(const floatx4*)(a32 + (size_t)(m0 + srow + 32) * lda + k0 + skk + 4);
      #pragma unroll
      for (int i = 0; i < 4; i++) {
        av0[i] = (short)f2bf(f0[i]); av0[4 + i] = (short)f2bf(f1[i]);
        av1[i] = (short)f2bf(f2[i]); av1[4 + i] = (short)f2bf(f3[i]);
      }
    } else {
      av0 = *(const short8*)(a16 + (size_t)(m0 + srow) * lda + k0 + skk);
      av1 = *(const short8*)(a16 + (size_t)(m0 + srow + 32) * lda + k0 + skk);
    }
    bv0 = *(const short8*)(Bt + (size_t)(n0 + srow) * ldb + k0 + skk);
    bv1 = *(const short8*)(Bt + (size_t)(n0 + srow + 32) * ldb + k0 + skk);
    __syncthreads();
    *(short8*)&A_s[srow][skk] = av0;
    *(short8*)&A_s[32 + srow][skk] = av1;
    *(short8*)&B_s[srow][skk] = bv0;
    *(short8*)&B_s[32 + srow][skk] = bv1;
    __syncthreads();
    #pragma unroll
    for (int ks = 0; ks < 2; ks++) {
      short8 a0 = *(const short8*)&A_s[mb + fr][ks * 32 + fq * 8];
      short8 a1 = *(const short8*)&A_s[mb + 16 + fr][ks * 32 + fq * 8];
      short8 b0 = *(const short8*)&B_s[nb + fr][ks * 32 + fq * 8];
      short8 b1 = *(const short8*)&B_s[nb + 16 + fr][ks * 32 + fq * 8];
      acc[0][0] = MFMA16x32(a0, b0, acc[0][0]);
      acc[0][1] = MFMA16x32(a0, b1, acc[0][1]);
      acc[1][0] = MFMA16x32(a1, b0, acc[1][0]);
      acc[1][1] = MFMA16x32(a1, b1, acc[1][1]);
    }
  }
  #pragma unroll
  for (int mi = 0; mi < 2; mi++)
    #pragma unroll
    for (int ni = 0; ni < 2; ni++)
      #pragma unroll
      for (int j = 0; j < 4; j++) {
        int row = m0 + mb + mi * 16 + fq * 4 + j;
        int col = n0 + nb + ni * 16 + fr;
        float v = acc[mi][ni][j];
        if (bias) v += bias[col];
        if constexpr (C16) ((unsigned short*)Cp)[(size_t)row * ldc + col] = f2bf(v);
        else               ((float*)Cp)[(size_t)row * ldc + col] = v;
      }
}

// ---------------- 128x64 GLDS+swizzle batch gemm, XCD-chunked, counted-vmcnt (round-15) ----------------
template <bool C16>
__global__ __launch_bounds__(256) void k_gemm2(
    const unsigned short* __restrict__ A, long lda,
    const unsigned short* __restrict__ Bt, long ldb,
    const float* __restrict__ bias,
    void* __restrict__ Cp, long ldc, int K) {
  __shared__ __attribute__((aligned(1024))) unsigned short lds[2][192 * 64];
  int per = gridDim.x >> 3;
  int flat = (blockIdx.x & 7) * per + (blockIdx.x >> 3);  // XCD-chunked bijection
  int n0 = (flat & 15) * 64, m0 = (flat >> 4) * 128;
  int tid = threadIdx.x, w = tid >> 6, lane = tid & 63;
  int lr = lane >> 3, ce = ((lane & 7) ^ lr) << 3;
  int fr = lane & 15, fq = lane >> 4;
  int xr = (fr & 7) << 3;
  int wm = (w & 1) * 64, wn = (w >> 1) * 32;
  auto stage = [&](int buf, int k0) {
    #pragma unroll
    for (int q = 0; q < 6; q++) {
      int j = w * 6 + q;
      int rr = j * 8 + lr;
      const unsigned short* src = (rr < 128)
        ? A + (size_t)(m0 + rr) * lda + k0 + ce
        : Bt + (size_t)(n0 + rr - 128) * ldb + k0 + ce;
      GLDS(src, &lds[buf][j * 512]);
    }
  };
  floatx4 acc[4][2] = {};
  int niter = K / 64;
  stage(0, 0); stage(1, 64);
  for (int ks = 0; ks < niter; ks++) {
    int cur = ks & 1;
    if (ks + 1 < niter) asm volatile("s_waitcnt vmcnt(6)" ::: "memory");
    else                asm volatile("s_waitcnt vmcnt(0)" ::: "memory");
    __builtin_amdgcn_s_barrier();
    __builtin_amdgcn_sched_barrier(0);
    const unsigned short* L = lds[cur];
    __builtin_amdgcn_s_setprio(1);
    #pragma unroll
    for (int kh = 0; kh < 2; kh++) {
      int kb = kh * 32 + fq * 8;
      short8 af[4], bf[2];
      #pragma unroll
      for (int i = 0; i < 4; i++)
        af[i] = *(const short8*)&L[((wm + i * 16 + fr) * 64 + kb) ^ xr];
      #pragma unroll
      for (int i = 0; i < 2; i++)
        bf[i] = *(const short8*)&L[((128 + wn + i * 16 + fr) * 64 + kb) ^ xr];
      #pragma unroll
      for (int mi = 0; mi < 4; mi++)
        #pragma unroll
        for (int ni = 0; ni < 2; ni++)
          acc[mi][ni] = MFMA16x32(af[mi], bf[ni], acc[mi][ni]);
    }
    __builtin_amdgcn_s_setprio(0);
    __builtin_amdgcn_sched_barrier(0);
    __builtin_amdgcn_s_barrier();
    if (ks + 2 < niter) stage(cur, (ks + 2) * 64);
  }
  #pragma unroll
  for (int mi = 0; mi < 4; mi++)
    #pragma unroll
    for (int ni = 0; ni < 2; ni++)
      #pragma unroll
      for (int j = 0; j < 4; j++) {
        int row = m0 + wm + mi * 16 + fq * 4 + j;
        int col = n0 + wn + ni * 16 + fr;
        float v = acc[mi][ni][j];
        if (bias) v += bias[col];
        if constexpr (C16) ((unsigned short*)Cp)[(size_t)row * ldc + col] = f2bf(v);
        else               ((float*)Cp)[(size_t)row * ldc + col] = v;
      }
}

// ---------------- per-step k_gru: BM=32, 512 threads, grid 512 (2 blocks/CU, 4 waves/SIMD) ----------------
// grid 512 = 64 n_t x 8 m_t (XCD-grouped). Wave w: rh=w&1 row-16-half, wc=(w>>1)&1 col-group,
// kh=w>>2 K-half. LDS: 2 bufs x 128 rows x 64 (rows 0..31 A, 32..127 WT exact) = 32KB.
__global__ __launch_bounds__(512) void k_gru(
    int t, const unsigned short* __restrict__ astk, const unsigned short* __restrict__ hnb_r,
    const unsigned short* __restrict__ wt,
    const float* __restrict__ gbi, const float* __restrict__ gbh,
    const unsigned char* __restrict__ reset,
    float* __restrict__ h_f32, unsigned short* __restrict__ hnb_w,
    unsigned short* __restrict__ hs_bf, float* __restrict__ out) {
  __shared__ __attribute__((aligned(1024))) unsigned short lds[2][128 * 64];
  int raw = blockIdx.x;
  int xcd = raw & 7, ii = raw >> 3;              // ii 0..63
  int n_t = xcd * 8 + (ii & 7), m_t = ii >> 3;   // n_t 0..63, m_t 0..7
  int m0 = m_t * 32;
  int tid = threadIdx.x, w = tid >> 6, lane = tid & 63;
  int lr = lane >> 3;
  int ce = ((lane & 7) ^ lr) << 3;       // pre-swizzled source col (elem units)
  int fr = lane & 15, fq = lane >> 4;
  int xr = (fr & 7) << 3;                // read-side XOR (short units)
  int rh = w & 1, wc = (w >> 1) & 1, kh = w >> 2;

  auto stage = [&](int buf, int k0) {
    #pragma unroll
    for (int q = 0; q < 2; q++) {
      int j = w * 2 + q;                 // j 0..15 -> rows 0..127
      int rr = j * 8 + lr;
      const unsigned short* src;
      if (rr < 32) {
        src = (k0 < HID) ? astk + (size_t)(m0 + rr) * HID + (k0 + ce)
                         : hnb_r + (size_t)(m0 + rr) * DETER + (k0 - HID + ce);
      } else {
        src = wt + (size_t)(n_t * 96 + rr - 32) * 3072 + (k0 + ce);
      }
      GLDS(src, &lds[buf][j * 512]);
    }
  };

  floatx4 acc[4] = {};   // r,u,ic,hc -- this wave's (rh,wc,kh) role
  stage(0, 0); stage(1, 64);
  for (int ks = 0; ks < 48; ks++) {
    int cur = ks & 1;
    if (ks < 47) asm volatile("s_waitcnt vmcnt(2)" ::: "memory");
    else         asm volatile("s_waitcnt vmcnt(0)" ::: "memory");
    __builtin_amdgcn_s_barrier();
    __builtin_amdgcn_sched_barrier(0);
    const unsigned short* L = lds[cur];
    __builtin_amdgcn_s_setprio(1);
    {
      int kb = kh * 32 + fq * 8;
      short8 a0 = *(const short8*)&L[((rh * 16 + fr) * 64 + kb) ^ xr];
      short8 br = *(const short8*)&L[((32 + wc * 48 + fr) * 64 + kb) ^ xr];
      short8 bu = *(const short8*)&L[((32 + wc * 48 + 16 + fr) * 64 + kb) ^ xr];
      short8 bc = *(const short8*)&L[((32 + wc * 48 + 32 + fr) * 64 + kb) ^ xr];
      acc[0] = MFMA16x32(a0, br, acc[0]);
      acc[1] = MFMA16x32(a0, bu, acc[1]);
      if (ks < 16) acc[2] = MFMA16x32(a0, bc, acc[2]);
      else         acc[3] = MFMA16x32(a0, bc, acc[3]);
    }
    __builtin_amdgcn_s_setprio(0);
    __builtin_amdgcn_sched_barrier(0);
    __builtin_amdgcn_s_barrier();
    if (ks + 2 < 48) stage(cur, (ks + 2) * 64);
  }
  // cross-wave kh reduction: waves 4..7 -> waves 0..3 (same rh,wc role). 16KB scratch.
  __syncthreads();
  float* red = (float*)lds;
  if (kh == 1) {
    int base = ((w - 4) * 64 + lane) * 16;
    #pragma unroll
    for (int g = 0; g < 4; g++)
      *(floatx4*)&red[base + g * 4] = acc[g];
  }
  __syncthreads();
  if (kh == 0) {
    int base = (w * 64 + lane) * 16;
    #pragma unroll
    for (int g = 0; g < 4; g++)
      acc[g] += *(const floatx4*)&red[base + g * 4];
    int jc = n_t * 32 + wc * 16 + fr;
    float bir = gbi[jc],        bhr = gbh[jc];
    float biu = gbi[jc + 2048], bhu = gbh[jc + 2048];
    float bic = gbi[jc + 4096], bhc = gbh[jc + 4096];
    #pragma unroll
    for (int j = 0; j < 4; j++) {
      int b = m0 + rh * 16 + fq * 4 + j;
      float r = sgm(acc[0][j] + bir + bhr);
      float u = sgm(acc[1][j] + biu + bhu);
      float c = tanhf(acc[2][j] + bic + r * (acc[3][j] + bhc));
      size_t hi = (size_t)b * DETER + jc;
      float hold = h_f32[hi];
      float hn = (1.f - u) * c + u * hold;
      out[((size_t)t * BDIM + b) * OUTW + 256 + jc] = hn;
      hs_bf[((size_t)t * BDIM + b) * DETER + jc] = f2bf(hn);
      float mn = (t + 1 < NSTEP && reset[(size_t)(t + 1) * BDIM + b]) ? 0.f : 1.f;
      float hm = hn * mn;
      h_f32[hi] = hm;
      hnb_w[hi] = f2bf(hm);
    }
  }
}

// ---------------- per-step k_ph: 512 threads (8 waves, kh-split), split-K=2 (round-13) ----------------
__global__ __launch_bounds__(512) void k_ph(
    int t, const unsigned short* __restrict__ hsbf, const unsigned short* __restrict__ pht,
    float* __restrict__ x2p) {
  __shared__ __attribute__((aligned(1024))) unsigned short lds[2][128 * 64];
  int raw = blockIdx.x;
  int n_t = raw & 15, m_t = (raw >> 4) & 7, kslc = raw >> 7;
  int m0 = m_t * 32, n0 = n_t * 64, koff = kslc * 1024;
  const unsigned short* hb = hsbf + (size_t)t * BDIM * DETER;
  int tid = threadIdx.x, w = tid >> 6, lane = tid & 63;
  int lr = lane >> 3;
  int ce = ((lane & 7) ^ lr) << 3;
  int fr = lane & 15, fq = lane >> 4;
  int xr = (fr & 7) << 3;
  int wc = w & 3, kh = w >> 2;

  auto stage = [&](int buf, int k0) {
    #pragma unroll
    for (int q = 0; q < 2; q++) {
      int j = w * 2 + q;                 // j 0..15 -> rows 0..127
      int rr = j * 8 + lr;
      const unsigned short* src;
      if (rr < 32) {
        src = hb + (size_t)(m0 + rr) * DETER + koff + k0 + ce;
      } else {
        int brow = rr - 32;
        if (brow > 63) brow = 63;        // pad rows: harmless duplicate load
        src = pht + (size_t)(n0 + brow) * DETER + koff + k0 + ce;
      }
      GLDS(src, &lds[buf][j * 512]);
    }
  };

  floatx4 acc[2] = {};
  stage(0, 0); stage(1, 64);
  for (int ks = 0; ks < 16; ks++) {
    int cur = ks & 1;
    if (ks < 15) asm volatile("s_waitcnt vmcnt(2)" ::: "memory");
    else         asm volatile("s_waitcnt vmcnt(0)" ::: "memory");
    __builtin_amdgcn_s_barrier();
    __builtin_amdgcn_sched_barrier(0);
    const unsigned short* L = lds[cur];
    __builtin_amdgcn_s_setprio(1);
    {
      int kb = kh * 32 + fq * 8;
      short8 a0 = *(const short8*)&L[((fr) * 64 + kb) ^ xr];
      short8 a1 = *(const short8*)&L[((16 + fr) * 64 + kb) ^ xr];
      short8 bw = *(const short8*)&L[((32 + wc * 16 + fr) * 64 + kb) ^ xr];
      acc[0] = MFMA16x32(a0, bw, acc[0]);
      acc[1] = MFMA16x32(a1, bw, acc[1]);
    }
    __builtin_amdgcn_s_setprio(0);
    __builtin_amdgcn_sched_barrier(0);
    __builtin_amdgcn_s_barrier();
    if (ks + 2 < 16) stage(cur, (ks + 2) * 64);
  }
  // kh reduction: waves 4..7 -> 0..3
  __syncthreads();
  float* red = (float*)lds;
  if (kh == 1) {
    int p = w - 4;
    #pragma unroll
    for (int g = 0; g < 2; g++)
      *(floatx4*)&red[((g * 4 + p) * 64 + lane) * 4] = acc[g];
  }
  __syncthreads();
  if (kh == 0) {
    int p = w;
    #pragma unroll
    for (int g = 0; g < 2; g++)
      acc[g] += *(const floatx4*)&red[((g * 4 + p) * 64 + lane) * 4];
    int col = n0 + wc * 16 + fr;
    #pragma unroll
    for (int mi = 0; mi < 2; mi++)
      #pragma unroll
      for (int j = 0; j < 4; j++)
        x2p[(size_t)(kslc * BDIM + m0 + mi * 16 + fq * 4 + j) * HID + col] = acc[mi][j];
  }
}

// ---------------- per-step k_post (zwb bf16) ----------------
__global__ __launch_bounds__(256) void k_post(
    int t, const float* __restrict__ x2p, const float* __restrict__ ph_b,
    const unsigned short* __restrict__ eab,
    const float* __restrict__ pon_g, const float* __restrict__ pon_b,
    const unsigned short* __restrict__ pomb, const float* __restrict__ pom_b,
    const float* __restrict__ noises, const unsigned char* __restrict__ reset,
    const unsigned short* __restrict__ zwb, const unsigned short* __restrict__ xab,
    const float* __restrict__ in_g, const float* __restrict__ in_b,
    float* __restrict__ out, unsigned short* __restrict__ astk) {
  int b = blockIdx.x, tid = threadIdx.x;
  __shared__ float pin[HID];
  __shared__ float red[8];
  __shared__ float post[128];
  __shared__ float zm[64];
  __shared__ float pacc[256];
  int j0 = tid * 4;
  floatx4 x = *(const floatx4*)&x2p[(size_t)b * HID + j0];
  floatx4 x1 = *(const floatx4*)&x2p[(size_t)(BDIM + b) * HID + j0];
  floatx4 bb = *(const floatx4*)&ph_b[j0];
  short4v e4 = *(const short4v*)&eab[((size_t)t * BDIM + b) * HID + j0];
  #pragma unroll
  for (int i = 0; i < 4; i++) x[i] += x1[i] + bb[i] + bf2f((unsigned short)e4[i]);
  float s = x[0] + x[1] + x[2] + x[3];
  float q = x[0]*x[0] + x[1]*x[1] + x[2]*x[2] + x[3]*x[3];
  block_sum2(s, q, red, tid);
  float mean = s * (1.f / HID);
  float rstd = rsqrtf(q * (1.f / HID) - mean * mean + LNEPS);
  floatx4 gg = *(const floatx4*)&pon_g[j0];
  floatx4 ob = *(const floatx4*)&pon_b[j0];
  floatx4 pv;
  #pragma unroll
  for (int i = 0; i < 4; i++) pv[i] = elu1((x[i] - mean) * rstd * gg[i] + ob[i]);
  *(floatx4*)&pin[j0] = pv;
  __syncthreads();
  {
    int col = tid & 127, half = tid >> 7;
    const unsigned short* pb = pomb + (size_t)(half * 512) * 128 + col;
    const float* pi = pin + half * 512;
    float a0 = 0, a1 = 0, a2 = 0, a3 = 0;
    #pragma unroll 8
    for (int k = 0; k < 512; k += 4) {
      a0 += pi[k]     * bf2f(pb[(size_t)k * 128]);
      a1 += pi[k + 1] * bf2f(pb[(size_t)(k + 1) * 128]);
      a2 += pi[k + 2] * bf2f(pb[(size_t)(k + 2) * 128]);
      a3 += pi[k + 3] * bf2f(pb[(size_t)(k + 3) * 128]);
    }
    pacc[tid] = (a0 + a1) + (a2 + a3);
  }
  __syncthreads();
  size_t ro = ((size_t)t * BDIM + b) * OUTW;
  if (tid < 128) {
    float p = pacc[tid] + pacc[tid + 128] + pom_b[tid];
    post[tid] = p;
    out[ro + 128 + tid] = p;
  }
  __syncthreads();
  if (tid < 64) {
    float mn = post[tid], raw = post[64 + tid];
    float std = 2.f * sgm(raw) + 0.1f;
    float z = mn + std * noises[((size_t)t * BDIM + b) * STOCH + tid];
    out[ro + 2304 + tid] = z;
    float mk = (t + 1 < NSTEP && reset[(size_t)(t + 1) * BDIM + b]) ? 0.f : 1.f;
    zm[tid] = z * mk;
  }
  __syncthreads();
  if (t + 1 < NSTEP) {
    short4v xa = *(const short4v*)&xab[((size_t)(t + 1) * BDIM + b) * HID + j0];
    floatx4 xn;
    #pragma unroll
    for (int i = 0; i < 4; i++) xn[i] = bf2f((unsigned short)xa[i]);
    #pragma unroll 8
    for (int k = 0; k < 64; k++) {
      short4v wv4 = *(const short4v*)&zwb[(size_t)k * HID + j0];
      float zk = zm[k];
      #pragma unroll
      for (int i = 0; i < 4; i++) xn[i] += zk * bf2f((unsigned short)wv4[i]);
    }
    float s2 = xn[0] + xn[1] + xn[2] + xn[3];
    float q2 = xn[0]*xn[0] + xn[1]*xn[1] + xn[2]*xn[2] + xn[3]*xn[3];
    block_sum2(s2, q2, red, tid);
    float mean2 = s2 * (1.f / HID);
    float rstd2 = rsqrtf(q2 * (1.f / HID) - mean2 * mean2 + LNEPS);
    floatx4 g2 = *(const floatx4*)&in_g[j0];
    floatx4 b2 = *(const floatx4*)&in_b[j0];
    short4v ov;
    #pragma unroll
    for (int i = 0; i < 4; i++)
      ov[i] = (short)f2bf(elu1((xn[i] - mean2) * rstd2 * g2[i] + b2[i]));
    *(short4v*)&astk[(size_t)b * HID + j0] = ov;
  }
}

// ---------------- t=0 input path ----------------
__global__ __launch_bounds__(256) void k_pre0(
    const float* __restrict__ z0, const unsigned char* __restrict__ reset,
    const float* __restrict__ z_w, const unsigned short* __restrict__ xab,
    const float* __restrict__ in_g, const float* __restrict__ in_b,
    unsigned short* __restrict__ astk) {
  int b = blockIdx.x, tid = threadIdx.x;
  __shared__ float zm[64];
  __shared__ float red[8];
  if (tid < 64) {
    float mk = reset[b] ? 0.f : 1.f;
    zm[tid] = z0[(size_t)b * STOCH + tid] * mk;
  }
  __syncthreads();
  int j0 = tid * 4;
  short4v xa = *(const short4v*)&xab[(size_t)b * HID + j0];
  floatx4 xn;
  #pragma unroll
  for (int i = 0; i < 4; i++) xn[i] = bf2f((unsigned short)xa[i]);
  #pragma unroll 8
  for (int k = 0; k < 64; k++) {
    floatx4 wv = *(const floatx4*)&z_w[(size_t)k * HID + j0];
    xn += zm[k] * wv;
  }
  float s = xn[0] + xn[1] + xn[2] + xn[3];
  float q = xn[0]*xn[0] + xn[1]*xn[1] + xn[2]*xn[2] + xn[3]*xn[3];
  block_sum2(s, q, red, tid);
  float mean = s * (1.f / HID);
  float rstd = rsqrtf(q * (1.f / HID) - mean * mean + LNEPS);
  short4v ov;
  #pragma unroll
  for (int i = 0; i < 4; i++)
    ov[i] = (short)f2bf(elu1((xn[i] - mean) * rstd * in_g[j0 + i] + in_b[j0 + i]));
  *(short4v*)&astk[(size_t)b * HID + j0] = ov;
}

// ---------------- batch LN+ELU (prior path, bf16 in/out) ----------------
__global__ __launch_bounds__(256) void k_ln_elu(
    const unsigned short* __restrict__ X, const float* __restrict__ g, const float* __restrict__ bb,
    unsigned short* __restrict__ Y) {
  int row = blockIdx.x, tid = threadIdx.x;
  __shared__ float red[8];
  int j0 = tid * 4;
  short4v v4 = *(const short4v*)&X[(size_t)row * HID + j0];
  floatx4 v;
  #pragma unroll
  for (int i = 0; i < 4; i++) v[i] = bf2f((unsigned short)v4[i]);
  float s = v[0] + v[1] + v[2] + v[3];
  float q = v[0]*v[0] + v[1]*v[1] + v[2]*v[2] + v[3]*v[3];
  block_sum2(s, q, red, tid);
  float mean = s * (1.f / HID);
  float rstd = rsqrtf(q * (1.f / HID) - mean * mean + LNEPS);
  short4v ov;
  #pragma unroll
  for (int i = 0; i < 4; i++)
    ov[i] = (short)f2bf(elu1((v[i] - mean) * rstd * g[j0 + i] + bb[j0 + i]));
  *(short4v*)&Y[(size_t)row * HID + j0] = ov;
}

extern "C" void kernel_launch(void* const* d_in, const int* in_sizes, int n_in,
                              void* d_out, int out_size, void* d_ws, size_t ws_size,
                              hipStream_t stream) {
  (void)in_sizes; (void)n_in; (void)out_size; (void)ws_size;
  const float* embed  = (const float*)d_in[0];
  const float* action = (const float*)d_in[1];
  const unsigned char* reset = (const unsigned char*)d_in[2];
  const float* h0     = (const float*)d_in[3];
  const float* z0     = (const float*)d_in[4];
  const float* noises = (const float*)d_in[5];
  const float* z_w    = (const float*)d_in[6];
  const float* z_b    = (const float*)d_in[7];
  const float* a_w    = (const float*)d_in[8];
  const float* in_g   = (const float*)d_in[9];
  const float* in_b   = (const float*)d_in[10];
  const float* gru_wi = (const float*)d_in[11];
  const float* gru_wh = (const float*)d_in[12];
  const float* gru_bi = (const float*)d_in[13];
  const float* gru_bh = (const float*)d_in[14];
  const float* ph_w   = (const float*)d_in[15];
  const float* ph_b   = (const float*)d_in[16];
  const float* pe_w   = (const float*)d_in[17];
  const float* pon_g  = (const float*)d_in[18];
  const float* pon_b  = (const float*)d_in[19];
  const float* pom_w  = (const float*)d_in[20];
  const float* pom_b  = (const float*)d_in[21];
  const float* prh_w  = (const float*)d_in[22];
  const float* prh_b  = (const float*)d_in[23];
  const float* prn_g  = (const float*)d_in[24];
  const float* prn_b  = (const float*)d_in[25];
  const float* prm_w  = (const float*)d_in[26];
  const float* prm_b  = (const float*)d_in[27];
  float* out = (float*)d_out;

  // ---- workspace carve (~186 MB) ----
  char* w = (char*)d_ws;
  auto carve = [&](size_t bytes) { char* p = w; w += (bytes + 255) & ~(size_t)255; return p; };
  unsigned short* WT   = (unsigned short*)carve((size_t)6144 * 3072 * 2);
  unsigned short* PHT  = (unsigned short*)carve((size_t)HID * DETER * 2);
  unsigned short* PET  = (unsigned short*)carve((size_t)HID * EMBD * 2);
  unsigned short* AWT  = (unsigned short*)carve((size_t)HID * 64 * 2);
  unsigned short* ZWB  = (unsigned short*)carve((size_t)STOCH * HID * 2);
  unsigned short* POMB = (unsigned short*)carve((size_t)HID * 128 * 2);
  unsigned short* PRHT = (unsigned short*)carve((size_t)HID * DETER * 2);
  unsigned short* PRMT = (unsigned short*)carve((size_t)128 * HID * 2);
  unsigned short* EAB  = (unsigned short*)carve((size_t)NSTEP * BDIM * HID * 2);  // EA bf16
  unsigned short* XPB  = (unsigned short*)carve((size_t)NSTEP * BDIM * HID * 2);  // prior x bf16
  unsigned short* XABP = (unsigned short*)carve((size_t)NSTEP * BDIM * HID * 2);  // XAB, later PRIN
  unsigned short* HSBF = (unsigned short*)carve((size_t)NSTEP * BDIM * DETER * 2);
  unsigned short* ASTK = (unsigned short*)carve((size_t)BDIM * HID * 2);
  unsigned short* HNB0 = (unsigned short*)carve((size_t)BDIM * DETER * 2);
  unsigned short* HNB1 = (unsigned short*)carve((size_t)BDIM * DETER * 2);
  float*          HF32 = (float*)carve((size_t)BDIM * DETER * 4);
  float*          X2P  = (float*)carve((size_t)2 * BDIM * HID * 4);
  unsigned short* EMBB = HSBF;   // overlay: embed-bf16 lives in HSBF until EA gemm done (pre-loop)

  dim3 tb(32, 8);
  // weight prep
  k_wt_gate<<<dim3(192, 96), tb, 0, stream>>>(gru_wi, gru_wh, WT);
  k_transpose_bf16<<<dim3(32, 64), tb, 0, stream>>>(ph_w, 1024, PHT, DETER);
  k_transpose_bf16<<<dim3(32, 48), tb, 0, stream>>>(pe_w, 1024, PET, EMBD);
  k_transpose_bf16<<<dim3(32, 2), tb, 0, stream>>>(a_w, 1024, AWT, 64);
  k_transpose_bf16<<<dim3(32, 64), tb, 0, stream>>>(prh_w, 1024, PRHT, DETER);
  k_transpose_bf16<<<dim3(4, 32), tb, 0, stream>>>(prm_w, 128, PRMT, HID);
  k_cvt_bf16<<<512, 256, 0, stream>>>(pom_w, POMB, HID * 128);
  k_cvt_bf16<<<256, 256, 0, stream>>>(z_w, ZWB, STOCH * HID);
  k_init_state<<<2048, 256, 0, stream>>>(h0, reset, HF32, HNB0);
  // embed -> bf16 (into HSBF overlay)
  k_cvt4<<<(NSTEP * BDIM * EMBD / 4 + 255) / 256, 256, 0, stream>>>(embed, EMBB, NSTEP * BDIM * EMBD / 4);
  // XAB = action @ a_w + z_b (bf16), all steps
  k_gemm<true, true><<<dim3(16, 200), 256, 0, stream>>>(action, 64, AWT, 64, z_b, XABP, HID, 64);
  // EA = embed @ pe_w (bf16), all steps  (128x64 tiles: 16 n x 100 m = 1600 WG)
  k_gemm2<true><<<1600, 256, 0, stream>>>(EMBB, EMBD, PET, EMBD, nullptr, EAB, HID, EMBD);
  // t=0 input path
  k_pre0<<<BDIM, 256, 0, stream>>>(z0, reset, z_w, XABP, in_g, in_b, ASTK);

  for (int t = 0; t < NSTEP; t++) {
    const unsigned short* hr = (t & 1) ? HNB1 : HNB0;
    unsigned short* hw = (t & 1) ? HNB0 : HNB1;
    k_gru<<<512, 512, 0, stream>>>(t, ASTK, hr, WT, gru_bi, gru_bh, reset,
                                   HF32, hw, HSBF, out);
    k_ph<<<256, 512, 0, stream>>>(t, HSBF, PHT, X2P);
    k_post<<<BDIM, 256, 0, stream>>>(t, X2P, ph_b, EAB, pon_g, pon_b, POMB, pom_b,
                                     noises, reset, ZWB, XABP, in_g, in_b, out, ASTK);
  }

  // batch prior: XP = hs @ prh_w + prh_b (bf16); PRIN overlays XABP
  k_gemm2<true><<<1600, 256, 0, stream>>>(HSBF, DETER, PRHT, DETER, prh_b, XPB, HID, DETER);
  k_ln_elu<<<NSTEP * BDIM, 256, 0, stream>>>(XPB, prn_g, prn_b, XABP);
  k_gemm<false, false><<<dim3(2, 200), 256, 0, stream>>>(XABP, HID, PRMT, HID, prm_b, out, OUTW, HID);
}

// Round 17
// 2599.788 us; speedup vs baseline: 1.0945x; 1.0205x over previous
//
#include <hip/hip_runtime.h>
#include <hip/hip_bf16.h>

typedef __attribute__((ext_vector_type(8))) short short8;
typedef __attribute__((ext_vector_type(4))) short short4v;
typedef __attribute__((ext_vector_type(4))) float floatx4;

#define MFMA16x32(a, b, c) __builtin_amdgcn_mfma_f32_16x16x32_bf16((a), (b), (c), 0, 0, 0)
#define GLDS(gp, lp) __builtin_amdgcn_global_load_lds( \
    (__attribute__((address_space(1))) unsigned int*)(gp), \
    (__attribute__((address_space(3))) unsigned int*)(lp), 16, 0, 0)

#define NSTEP 50
#define BDIM  256
#define EMBD  1536
#define DETER 2048
#define STOCH 64
#define HID   1024
#define OUTW  2368   // 128 priors + 128 posts + 2048 h + 64 z
#define LNEPS 1e-3f

__device__ __forceinline__ unsigned short f2bf(float f) {
  union { float f; unsigned u; } v; v.f = f;
  unsigned r = v.u + 0x7fffu + ((v.u >> 16) & 1u);   // RNE
  return (unsigned short)(r >> 16);
}
__device__ __forceinline__ float bf2f(unsigned short h) {
  union { unsigned u; float f; } v; v.u = (unsigned)h << 16;
  return v.f;
}
__device__ __forceinline__ float sgm(float x) { return 1.f / (1.f + __expf(-x)); }
__device__ __forceinline__ float elu1(float x) { return x > 0.f ? x : expm1f(x); }

__device__ __forceinline__ void block_sum2(float& s, float& q, float* red, int tid) {
  #pragma unroll
  for (int m = 1; m < 64; m <<= 1) { s += __shfl_xor(s, m, 64); q += __shfl_xor(q, m, 64); }
  int w = tid >> 6;
  if ((tid & 63) == 0) { red[w * 2] = s; red[w * 2 + 1] = q; }
  __syncthreads();
  s = red[0] + red[2] + red[4] + red[6];
  q = red[1] + red[3] + red[5] + red[7];
}

// ---------------- weight prep ----------------
__global__ void k_transpose_bf16(const float* __restrict__ src, int N,
                                 unsigned short* __restrict__ dst, int ldd) {
  __shared__ float tile[32][33];
  int n0 = blockIdx.x * 32, k0 = blockIdx.y * 32;
  for (int i = threadIdx.y; i < 32; i += 8)
    tile[i][threadIdx.x] = src[(size_t)(k0 + i) * N + n0 + threadIdx.x];
  __syncthreads();
  for (int i = threadIdx.y; i < 32; i += 8)
    dst[(size_t)(n0 + i) * ldd + k0 + threadIdx.x] = f2bf(tile[threadIdx.x][i]);
}

// WT gate-interleaved: out row rr: j=(rr/48)*16+(rr&15), g=(rr%48)>>4, src col=g*2048+j
__global__ void k_wt_gate(const float* __restrict__ wi, const float* __restrict__ wh,
                          unsigned short* __restrict__ dst) {
  __shared__ float tile[32][33];
  int r0 = blockIdx.x * 32, k0 = blockIdx.y * 32;
  int rr = r0 + threadIdx.x;
  int j = (rr / 48) * 16 + (rr & 15), g = (rr % 48) >> 4;
  int c = g * 2048 + j;
  for (int i = threadIdx.y; i < 32; i += 8) {
    int k = k0 + i;
    tile[i][threadIdx.x] = (k < 1024) ? wi[(size_t)k * 6144 + c]
                                      : wh[(size_t)(k - 1024) * 6144 + c];
  }
  __syncthreads();
  for (int i = threadIdx.y; i < 32; i += 8)
    dst[(size_t)(r0 + i) * 3072 + k0 + threadIdx.x] = f2bf(tile[threadIdx.x][i]);
}

__global__ void k_cvt_bf16(const float* __restrict__ src, unsigned short* __restrict__ dst, int n) {
  int i = blockIdx.x * blockDim.x + threadIdx.x;
  if (i < n) dst[i] = f2bf(src[i]);
}

__global__ void k_cvt4(const float* __restrict__ src, unsigned short* __restrict__ dst, int n4) {
  int i = blockIdx.x * 256 + threadIdx.x;
  if (i < n4) {
    floatx4 v = ((const floatx4*)src)[i];
    short4v o;
    #pragma unroll
    for (int j = 0; j < 4; j++) o[j] = (short)f2bf(v[j]);
    ((short4v*)dst)[i] = o;
  }
}

__global__ void k_init_state(const float* __restrict__ h0, const unsigned char* __restrict__ reset,
                             float* __restrict__ h_f32, unsigned short* __restrict__ hnb0) {
  int i = blockIdx.x * 256 + threadIdx.x;
  if (i < BDIM * DETER) {
    float m = reset[i >> 11] ? 0.f : 1.f;
    float v = h0[i] * m;
    h_f32[i] = v;
    hnb0[i] = f2bf(v);
  }
}

// ---------------- old-style 64x64 gemm (XAB K=64 f32-A; final prior head) ----------------
template <bool AF32, bool C16>
__global__ __launch_bounds__(256) void k_gemm(
    const void* __restrict__ Ap, long lda,
    const unsigned short* __restrict__ Bt, long ldb,
    const float* __restrict__ bias,
    void* __restrict__ Cp, long ldc, int K) {
  __shared__ __attribute__((aligned(16))) short A_s[64][72];
  __shared__ __attribute__((aligned(16))) short B_s[64][72];
  int n0 = blockIdx.x * 64, m0 = blockIdx.y * 64;
  int tid = threadIdx.x, wave = tid >> 6, lane = tid & 63;
  int srow = tid >> 3, skk = (tid & 7) * 8;
  int fr = lane & 15, fq = lane >> 4;
  int mb = (wave & 1) * 32, nb = (wave >> 1) * 32;
  const unsigned short* a16 = (const unsigned short*)Ap;
  const float* a32 = (const float*)Ap;
  floatx4 acc[2][2] = {};
  for (int k0 = 0; k0 < K; k0 += 64) {
    short8 av0, av1, bv0, bv1;
    if constexpr (AF32) {
      floatx4 f0 = *(const floatx4*)(a32 + (size_t)(m0 + srow) * lda + k0 + skk);
      floatx4 f1 = *(const floatx4*)(a32 + (size_t)(m0 + srow) * lda + k0 + skk + 4);
      floatx4 f2 = *(const floatx4*)(a32 + (size_t)(m0 + srow + 32) * lda + k0 + skk);
      floatx4 f3 = *(const floatx4*)(a32 + (size_t)(m0 + srow + 32) * lda + k0 + skk + 4);
      #pragma unroll
      for (int i = 0; i < 4; i++) {
        av0[i] = (short)f2bf(f0[i]); av0[4 + i] = (short)f2bf(f1[i]);
        av1[i] = (short)f2bf(f2[i]); av1[4 + i] = (short)f2bf(f3[i]);
      }
    } else {
      av0 = *(const short8*)(a16 + (size_t)(m0 + srow) * lda + k0 + skk);
      av1 = *(const short8*)(a16 + (size_t)(m0 + srow + 32) * lda + k0 + skk);
    }
    bv0 = *(const short8*)(Bt + (size_t)(n0 + srow) * ldb + k0 + skk);
    bv1 = *(const short8*)(Bt + (size_t)(n0 + srow + 32) * ldb + k0 + skk);
    __syncthreads();
    *(short8*)&A_s[srow][skk] = av0;
    *(short8*)&A_s[32 + srow][skk] = av1;
    *(short8*)&B_s[srow][skk] = bv0;
    *(short8*)&B_s[32 + srow][skk] = bv1;
    __syncthreads();
    #pragma unroll
    for (int ks = 0; ks < 2; ks++) {
      short8 a0 = *(const short8*)&A_s[mb + fr][ks * 32 + fq * 8];
      short8 a1 = *(const short8*)&A_s[mb + 16 + fr][ks * 32 + fq * 8];
      short8 b0 = *(const short8*)&B_s[nb + fr][ks * 32 + fq * 8];
      short8 b1 = *(const short8*)&B_s[nb + 16 + fr][ks * 32 + fq * 8];
      acc[0][0] = MFMA16x32(a0, b0, acc[0][0]);
      acc[0][1] = MFMA16x32(a0, b1, acc[0][1]);
      acc[1][0] = MFMA16x32(a1, b0, acc[1][0]);
      acc[1][1] = MFMA16x32(a1, b1, acc[1][1]);
    }
  }
  #pragma unroll
  for (int mi = 0; mi < 2; mi++)
    #pragma unroll
    for (int ni = 0; ni < 2; ni++)
      #pragma unroll
      for (int j = 0; j < 4; j++) {
        int row = m0 + mb + mi * 16 + fq * 4 + j;
        int col = n0 + nb + ni * 16 + fr;
        float v = acc[mi][ni][j];
        if (bias) v += bias[col];
        if constexpr (C16) ((unsigned short*)Cp)[(size_t)row * ldc + col] = f2bf(v);
        else               ((float*)Cp)[(size_t)row * ldc + col] = v;
      }
}

// ---------------- 128x64 GLDS+swizzle batch gemm, XCD-chunked, counted-vmcnt (round-15) ----------------
template <bool C16>
__global__ __launch_bounds__(256) void k_gemm2(
    const unsigned short* __restrict__ A, long lda,
    const unsigned short* __restrict__ Bt, long ldb,
    const float* __restrict__ bias,
    void* __restrict__ Cp, long ldc, int K) {
  __shared__ __attribute__((aligned(1024))) unsigned short lds[2][192 * 64];
  int per = gridDim.x >> 3;
  int flat = (blockIdx.x & 7) * per + (blockIdx.x >> 3);  // XCD-chunked bijection
  int n0 = (flat & 15) * 64, m0 = (flat >> 4) * 128;
  int tid = threadIdx.x, w = tid >> 6, lane = tid & 63;
  int lr = lane >> 3, ce = ((lane & 7) ^ lr) << 3;
  int fr = lane & 15, fq = lane >> 4;
  int xr = (fr & 7) << 3;
  int wm = (w & 1) * 64, wn = (w >> 1) * 32;
  auto stage = [&](int buf, int k0) {
    #pragma unroll
    for (int q = 0; q < 6; q++) {
      int j = w * 6 + q;
      int rr = j * 8 + lr;
      const unsigned short* src = (rr < 128)
        ? A + (size_t)(m0 + rr) * lda + k0 + ce
        : Bt + (size_t)(n0 + rr - 128) * ldb + k0 + ce;
      GLDS(src, &lds[buf][j * 512]);
    }
  };
  floatx4 acc[4][2] = {};
  int niter = K / 64;
  stage(0, 0); stage(1, 64);
  for (int ks = 0; ks < niter; ks++) {
    int cur = ks & 1;
    if (ks + 1 < niter) asm volatile("s_waitcnt vmcnt(6)" ::: "memory");
    else                asm volatile("s_waitcnt vmcnt(0)" ::: "memory");
    __builtin_amdgcn_s_barrier();
    __builtin_amdgcn_sched_barrier(0);
    const unsigned short* L = lds[cur];
    __builtin_amdgcn_s_setprio(1);
    #pragma unroll
    for (int kh = 0; kh < 2; kh++) {
      int kb = kh * 32 + fq * 8;
      short8 af[4], bf[2];
      #pragma unroll
      for (int i = 0; i < 4; i++)
        af[i] = *(const short8*)&L[((wm + i * 16 + fr) * 64 + kb) ^ xr];
      #pragma unroll
      for (int i = 0; i < 2; i++)
        bf[i] = *(const short8*)&L[((128 + wn + i * 16 + fr) * 64 + kb) ^ xr];
      #pragma unroll
      for (int mi = 0; mi < 4; mi++)
        #pragma unroll
        for (int ni = 0; ni < 2; ni++)
          acc[mi][ni] = MFMA16x32(af[mi], bf[ni], acc[mi][ni]);
    }
    __builtin_amdgcn_s_setprio(0);
    __builtin_amdgcn_sched_barrier(0);
    __builtin_amdgcn_s_barrier();
    if (ks + 2 < niter) stage(cur, (ks + 2) * 64);
  }
  #pragma unroll
  for (int mi = 0; mi < 4; mi++)
    #pragma unroll
    for (int ni = 0; ni < 2; ni++)
      #pragma unroll
      for (int j = 0; j < 4; j++) {
        int row = m0 + wm + mi * 16 + fq * 4 + j;
        int col = n0 + wn + ni * 16 + fr;
        float v = acc[mi][ni][j];
        if (bias) v += bias[col];
        if constexpr (C16) ((unsigned short*)Cp)[(size_t)row * ldc + col] = f2bf(v);
        else               ((float*)Cp)[(size_t)row * ldc + col] = v;
      }
}

// ---------------- per-step k_gru: BM=32, 512 threads, grid 512 (round-16 passing) ----------------
__global__ __launch_bounds__(512) void k_gru(
    int t, const unsigned short* __restrict__ astk, const unsigned short* __restrict__ hnb_r,
    const unsigned short* __restrict__ wt,
    const float* __restrict__ gbi, const float* __restrict__ gbh,
    const unsigned char* __restrict__ reset,
    float* __restrict__ h_f32, unsigned short* __restrict__ hnb_w,
    unsigned short* __restrict__ hs_bf, float* __restrict__ out) {
  __shared__ __attribute__((aligned(1024))) unsigned short lds[2][128 * 64];
  int raw = blockIdx.x;
  int xcd = raw & 7, ii = raw >> 3;              // ii 0..63
  int n_t = xcd * 8 + (ii & 7), m_t = ii >> 3;   // n_t 0..63, m_t 0..7
  int m0 = m_t * 32;
  int tid = threadIdx.x, w = tid >> 6, lane = tid & 63;
  int lr = lane >> 3;
  int ce = ((lane & 7) ^ lr) << 3;       // pre-swizzled source col (elem units)
  int fr = lane & 15, fq = lane >> 4;
  int xr = (fr & 7) << 3;                // read-side XOR (short units)
  int rh = w & 1, wc = (w >> 1) & 1, kh = w >> 2;

  auto stage = [&](int buf, int k0) {
    #pragma unroll
    for (int q = 0; q < 2; q++) {
      int j = w * 2 + q;                 // j 0..15 -> rows 0..127
      int rr = j * 8 + lr;
      const unsigned short* src;
      if (rr < 32) {
        src = (k0 < HID) ? astk + (size_t)(m0 + rr) * HID + (k0 + ce)
                         : hnb_r + (size_t)(m0 + rr) * DETER + (k0 - HID + ce);
      } else {
        src = wt + (size_t)(n_t * 96 + rr - 32) * 3072 + (k0 + ce);
      }
      GLDS(src, &lds[buf][j * 512]);
    }
  };

  floatx4 acc[4] = {};   // r,u,ic,hc -- this wave's (rh,wc,kh) role
  stage(0, 0); stage(1, 64);
  for (int ks = 0; ks < 48; ks++) {
    int cur = ks & 1;
    if (ks < 47) asm volatile("s_waitcnt vmcnt(2)" ::: "memory");
    else         asm volatile("s_waitcnt vmcnt(0)" ::: "memory");
    __builtin_amdgcn_s_barrier();
    __builtin_amdgcn_sched_barrier(0);
    const unsigned short* L = lds[cur];
    __builtin_amdgcn_s_setprio(1);
    {
      int kb = kh * 32 + fq * 8;
      short8 a0 = *(const short8*)&L[((rh * 16 + fr) * 64 + kb) ^ xr];
      short8 br = *(const short8*)&L[((32 + wc * 48 + fr) * 64 + kb) ^ xr];
      short8 bu = *(const short8*)&L[((32 + wc * 48 + 16 + fr) * 64 + kb) ^ xr];
      short8 bc = *(const short8*)&L[((32 + wc * 48 + 32 + fr) * 64 + kb) ^ xr];
      acc[0] = MFMA16x32(a0, br, acc[0]);
      acc[1] = MFMA16x32(a0, bu, acc[1]);
      if (ks < 16) acc[2] = MFMA16x32(a0, bc, acc[2]);
      else         acc[3] = MFMA16x32(a0, bc, acc[3]);
    }
    __builtin_amdgcn_s_setprio(0);
    __builtin_amdgcn_sched_barrier(0);
    __builtin_amdgcn_s_barrier();
    if (ks + 2 < 48) stage(cur, (ks + 2) * 64);
  }
  // cross-wave kh reduction: waves 4..7 -> waves 0..3 (same rh,wc role). 16KB scratch.
  __syncthreads();
  float* red = (float*)lds;
  if (kh == 1) {
    int base = ((w - 4) * 64 + lane) * 16;
    #pragma unroll
    for (int g = 0; g < 4; g++)
      *(floatx4*)&red[base + g * 4] = acc[g];
  }
  __syncthreads();
  if (kh == 0) {
    int base = (w * 64 + lane) * 16;
    #pragma unroll
    for (int g = 0; g < 4; g++)
      acc[g] += *(const floatx4*)&red[base + g * 4];
    int jc = n_t * 32 + wc * 16 + fr;
    float bir = gbi[jc],        bhr = gbh[jc];
    float biu = gbi[jc + 2048], bhu = gbh[jc + 2048];
    float bic = gbi[jc + 4096], bhc = gbh[jc + 4096];
    #pragma unroll
    for (int j = 0; j < 4; j++) {
      int b = m0 + rh * 16 + fq * 4 + j;
      float r = sgm(acc[0][j] + bir + bhr);
      float u = sgm(acc[1][j] + biu + bhu);
      float c = tanhf(acc[2][j] + bic + r * (acc[3][j] + bhc));
      size_t hi = (size_t)b * DETER + jc;
      float hold = h_f32[hi];
      float hn = (1.f - u) * c + u * hold;
      out[((size_t)t * BDIM + b) * OUTW + 256 + jc] = hn;
      hs_bf[((size_t)t * BDIM + b) * DETER + jc] = f2bf(hn);
      float mn = (t + 1 < NSTEP && reset[(size_t)(t + 1) * BDIM + b]) ? 0.f : 1.f;
      float hm = hn * mn;
      h_f32[hi] = hm;
      hnb_w[hi] = f2bf(hm);
    }
  }
}

// ---------------- per-step k_ph: 512 threads, split-K=4, grid 512 (2 blocks/CU) ----------------
// raw: n_t = raw&15 (64 cols), m_t = (raw>>4)&7 (32 rows), kslc = raw>>7 (0..3, K=512 each).
__global__ __launch_bounds__(512) void k_ph(
    int t, const unsigned short* __restrict__ hsbf, const unsigned short* __restrict__ pht,
    float* __restrict__ x2p) {
  __shared__ __attribute__((aligned(1024))) unsigned short lds[2][128 * 64];
  int raw = blockIdx.x;
  int n_t = raw & 15, m_t = (raw >> 4) & 7, kslc = raw >> 7;
  int m0 = m_t * 32, n0 = n_t * 64, koff = kslc * 512;
  const unsigned short* hb = hsbf + (size_t)t * BDIM * DETER;
  int tid = threadIdx.x, w = tid >> 6, lane = tid & 63;
  int lr = lane >> 3;
  int ce = ((lane & 7) ^ lr) << 3;
  int fr = lane & 15, fq = lane >> 4;
  int xr = (fr & 7) << 3;
  int wc = w & 3, kh = w >> 2;

  auto stage = [&](int buf, int k0) {
    #pragma unroll
    for (int q = 0; q < 2; q++) {
      int j = w * 2 + q;                 // j 0..15 -> rows 0..127
      int rr = j * 8 + lr;
      const unsigned short* src;
      if (rr < 32) {
        src = hb + (size_t)(m0 + rr) * DETER + koff + k0 + ce;
      } else {
        int brow = rr - 32;
        if (brow > 63) brow = 63;        // pad rows: harmless duplicate load
        src = pht + (size_t)(n0 + brow) * DETER + koff + k0 + ce;
      }
      GLDS(src, &lds[buf][j * 512]);
    }
  };

  floatx4 acc[2] = {};
  stage(0, 0); stage(1, 64);
  for (int ks = 0; ks < 8; ks++) {
    int cur = ks & 1;
    if (ks < 7) asm volatile("s_waitcnt vmcnt(2)" ::: "memory");
    else        asm volatile("s_waitcnt vmcnt(0)" ::: "memory");
    __builtin_amdgcn_s_barrier();
    __builtin_amdgcn_sched_barrier(0);
    const unsigned short* L = lds[cur];
    __builtin_amdgcn_s_setprio(1);
    {
      int kb = kh * 32 + fq * 8;
      short8 a0 = *(const short8*)&L[((fr) * 64 + kb) ^ xr];
      short8 a1 = *(const short8*)&L[((16 + fr) * 64 + kb) ^ xr];
      short8 bw = *(const short8*)&L[((32 + wc * 16 + fr) * 64 + kb) ^ xr];
      acc[0] = MFMA16x32(a0, bw, acc[0]);
      acc[1] = MFMA16x32(a1, bw, acc[1]);
    }
    __builtin_amdgcn_s_setprio(0);
    __builtin_amdgcn_sched_barrier(0);
    __builtin_amdgcn_s_barrier();
    if (ks + 2 < 8) stage(cur, (ks + 2) * 64);
  }
  // kh reduction: waves 4..7 -> 0..3
  __syncthreads();
  float* red = (float*)lds;
  if (kh == 1) {
    int p = w - 4;
    #pragma unroll
    for (int g = 0; g < 2; g++)
      *(floatx4*)&red[((g * 4 + p) * 64 + lane) * 4] = acc[g];
  }
  __syncthreads();
  if (kh == 0) {
    int p = w;
    #pragma unroll
    for (int g = 0; g < 2; g++)
      acc[g] += *(const floatx4*)&red[((g * 4 + p) * 64 + lane) * 4];
    int col = n0 + wc * 16 + fr;
    #pragma unroll
    for (int mi = 0; mi < 2; mi++)
      #pragma unroll
      for (int j = 0; j < 4; j++)
        x2p[(size_t)(kslc * BDIM + m0 + mi * 16 + fq * 4 + j) * HID + col] = acc[mi][j];
  }
}

// ---------------- per-step k_post (4 x2p partials) ----------------
__global__ __launch_bounds__(256) void k_post(
    int t, const float* __restrict__ x2p, const float* __restrict__ ph_b,
    const unsigned short* __restrict__ eab,
    const float* __restrict__ pon_g, const float* __restrict__ pon_b,
    const unsigned short* __restrict__ pomb, const float* __restrict__ pom_b,
    const float* __restrict__ noises, const unsigned char* __restrict__ reset,
    const unsigned short* __restrict__ zwb, const unsigned short* __restrict__ xab,
    const float* __restrict__ in_g, const float* __restrict__ in_b,
    float* __restrict__ out, unsigned short* __restrict__ astk) {
  int b = blockIdx.x, tid = threadIdx.x;
  __shared__ float pin[HID];
  __shared__ float red[8];
  __shared__ float post[128];
  __shared__ float zm[64];
  __shared__ float pacc[256];
  int j0 = tid * 4;
  floatx4 x = *(const floatx4*)&x2p[(size_t)b * HID + j0];
  #pragma unroll
  for (int p = 1; p < 4; p++) {
    floatx4 xp = *(const floatx4*)&x2p[(size_t)(p * BDIM + b) * HID + j0];
    #pragma unroll
    for (int i = 0; i < 4; i++) x[i] += xp[i];
  }
  floatx4 bb = *(const floatx4*)&ph_b[j0];
  short4v e4 = *(const short4v*)&eab[((size_t)t * BDIM + b) * HID + j0];
  #pragma unroll
  for (int i = 0; i < 4; i++) x[i] += bb[i] + bf2f((unsigned short)e4[i]);
  float s = x[0] + x[1] + x[2] + x[3];
  float q = x[0]*x[0] + x[1]*x[1] + x[2]*x[2] + x[3]*x[3];
  block_sum2(s, q, red, tid);
  float mean = s * (1.f / HID);
  float rstd = rsqrtf(q * (1.f / HID) - mean * mean + LNEPS);
  floatx4 gg = *(const floatx4*)&pon_g[j0];
  floatx4 ob = *(const floatx4*)&pon_b[j0];
  floatx4 pv;
  #pragma unroll
  for (int i = 0; i < 4; i++) pv[i] = elu1((x[i] - mean) * rstd * gg[i] + ob[i]);
  *(floatx4*)&pin[j0] = pv;
  __syncthreads();
  {
    int col = tid & 127, half = tid >> 7;
    const unsigned short* pb = pomb + (size_t)(half * 512) * 128 + col;
    const float* pi = pin + half * 512;
    float a0 = 0, a1 = 0, a2 = 0, a3 = 0;
    #pragma unroll 8
    for (int k = 0; k < 512; k += 4) {
      a0 += pi[k]     * bf2f(pb[(size_t)k * 128]);
      a1 += pi[k + 1] * bf2f(pb[(size_t)(k + 1) * 128]);
      a2 += pi[k + 2] * bf2f(pb[(size_t)(k + 2) * 128]);
      a3 += pi[k + 3] * bf2f(pb[(size_t)(k + 3) * 128]);
    }
    pacc[tid] = (a0 + a1) + (a2 + a3);
  }
  __syncthreads();
  size_t ro = ((size_t)t * BDIM + b) * OUTW;
  if (tid < 128) {
    float p = pacc[tid] + pacc[tid + 128] + pom_b[tid];
    post[tid] = p;
    out[ro + 128 + tid] = p;
  }
  __syncthreads();
  if (tid < 64) {
    float mn = post[tid], raw = post[64 + tid];
    float std = 2.f * sgm(raw) + 0.1f;
    float z = mn + std * noises[((size_t)t * BDIM + b) * STOCH + tid];
    out[ro + 2304 + tid] = z;
    float mk = (t + 1 < NSTEP && reset[(size_t)(t + 1) * BDIM + b]) ? 0.f : 1.f;
    zm[tid] = z * mk;
  }
  __syncthreads();
  if (t + 1 < NSTEP) {
    short4v xa = *(const short4v*)&xab[((size_t)(t + 1) * BDIM + b) * HID + j0];
    floatx4 xn;
    #pragma unroll
    for (int i = 0; i < 4; i++) xn[i] = bf2f((unsigned short)xa[i]);
    #pragma unroll 8
    for (int k = 0; k < 64; k++) {
      short4v wv4 = *(const short4v*)&zwb[(size_t)k * HID + j0];
      float zk = zm[k];
      #pragma unroll
      for (int i = 0; i < 4; i++) xn[i] += zk * bf2f((unsigned short)wv4[i]);
    }
    float s2 = xn[0] + xn[1] + xn[2] + xn[3];
    float q2 = xn[0]*xn[0] + xn[1]*xn[1] + xn[2]*xn[2] + xn[3]*xn[3];
    block_sum2(s2, q2, red, tid);
    float mean2 = s2 * (1.f / HID);
    float rstd2 = rsqrtf(q2 * (1.f / HID) - mean2 * mean2 + LNEPS);
    floatx4 g2 = *(const floatx4*)&in_g[j0];
    floatx4 b2 = *(const floatx4*)&in_b[j0];
    short4v ov;
    #pragma unroll
    for (int i = 0; i < 4; i++)
      ov[i] = (short)f2bf(elu1((xn[i] - mean2) * rstd2 * g2[i] + b2[i]));
    *(short4v*)&astk[(size_t)b * HID + j0] = ov;
  }
}

// ---------------- t=0 input path ----------------
__global__ __launch_bounds__(256) void k_pre0(
    const float* __restrict__ z0, const unsigned char* __restrict__ reset,
    const float* __restrict__ z_w, const unsigned short* __restrict__ xab,
    const float* __restrict__ in_g, const float* __restrict__ in_b,
    unsigned short* __restrict__ astk) {
  int b = blockIdx.x, tid = threadIdx.x;
  __shared__ float zm[64];
  __shared__ float red[8];
  if (tid < 64) {
    float mk = reset[b] ? 0.f : 1.f;
    zm[tid] = z0[(size_t)b * STOCH + tid] * mk;
  }
  __syncthreads();
  int j0 = tid * 4;
  short4v xa = *(const short4v*)&xab[(size_t)b * HID + j0];
  floatx4 xn;
  #pragma unroll
  for (int i = 0; i < 4; i++) xn[i] = bf2f((unsigned short)xa[i]);
  #pragma unroll 8
  for (int k = 0; k < 64; k++) {
    floatx4 wv = *(const floatx4*)&z_w[(size_t)k * HID + j0];
    xn += zm[k] * wv;
  }
  float s = xn[0] + xn[1] + xn[2] + xn[3];
  float q = xn[0]*xn[0] + xn[1]*xn[1] + xn[2]*xn[2] + xn[3]*xn[3];
  block_sum2(s, q, red, tid);
  float mean = s * (1.f / HID);
  float rstd = rsqrtf(q * (1.f / HID) - mean * mean + LNEPS);
  short4v ov;
  #pragma unroll
  for (int i = 0; i < 4; i++)
    ov[i] = (short)f2bf(elu1((xn[i] - mean) * rstd * in_g[j0 + i] + in_b[j0 + i]));
  *(short4v*)&astk[(size_t)b * HID + j0] = ov;
}

// ---------------- batch LN+ELU (prior path, bf16 in/out) ----------------
__global__ __launch_bounds__(256) void k_ln_elu(
    const unsigned short* __restrict__ X, const float* __restrict__ g, const float* __restrict__ bb,
    unsigned short* __restrict__ Y) {
  int row = blockIdx.x, tid = threadIdx.x;
  __shared__ float red[8];
  int j0 = tid * 4;
  short4v v4 = *(const short4v*)&X[(size_t)row * HID + j0];
  floatx4 v;
  #pragma unroll
  for (int i = 0; i < 4; i++) v[i] = bf2f((unsigned short)v4[i]);
  float s = v[0] + v[1] + v[2] + v[3];
  float q = v[0]*v[0] + v[1]*v[1] + v[2]*v[2] + v[3]*v[3];
  block_sum2(s, q, red, tid);
  float mean = s * (1.f / HID);
  float rstd = rsqrtf(q * (1.f / HID) - mean * mean + LNEPS);
  short4v ov;
  #pragma unroll
  for (int i = 0; i < 4; i++)
    ov[i] = (short)f2bf(elu1((v[i] - mean) * rstd * g[j0 + i] + bb[j0 + i]));
  *(short4v*)&Y[(size_t)row * HID + j0] = ov;
}

extern "C" void kernel_launch(void* const* d_in, const int* in_sizes, int n_in,
                              void* d_out, int out_size, void* d_ws, size_t ws_size,
                              hipStream_t stream) {
  (void)in_sizes; (void)n_in; (void)out_size; (void)ws_size;
  const float* embed  = (const float*)d_in[0];
  const float* action = (const float*)d_in[1];
  const unsigned char* reset = (const unsigned char*)d_in[2];
  const float* h0     = (const float*)d_in[3];
  const float* z0     = (const float*)d_in[4];
  const float* noises = (const float*)d_in[5];
  const float* z_w    = (const float*)d_in[6];
  const float* z_b    = (const float*)d_in[7];
  const float* a_w    = (const float*)d_in[8];
  const float* in_g   = (const float*)d_in[9];
  const float* in_b   = (const float*)d_in[10];
  const float* gru_wi = (const float*)d_in[11];
  const float* gru_wh = (const float*)d_in[12];
  const float* gru_bi = (const float*)d_in[13];
  const float* gru_bh = (const float*)d_in[14];
  const float* ph_w   = (const float*)d_in[15];
  const float* ph_b   = (const float*)d_in[16];
  const float* pe_w   = (const float*)d_in[17];
  const float* pon_g  = (const float*)d_in[18];
  const float* pon_b  = (const float*)d_in[19];
  const float* pom_w  = (const float*)d_in[20];
  const float* pom_b  = (const float*)d_in[21];
  const float* prh_w  = (const float*)d_in[22];
  const float* prh_b  = (const float*)d_in[23];
  const float* prn_g  = (const float*)d_in[24];
  const float* prn_b  = (const float*)d_in[25];
  const float* prm_w  = (const float*)d_in[26];
  const float* prm_b  = (const float*)d_in[27];
  float* out = (float*)d_out;

  // ---- workspace carve (~186 MB) ----
  char* w = (char*)d_ws;
  auto carve = [&](size_t bytes) { char* p = w; w += (bytes + 255) & ~(size_t)255; return p; };
  unsigned short* WT   = (unsigned short*)carve((size_t)6144 * 3072 * 2);
  unsigned short* PHT  = (unsigned short*)carve((size_t)HID * DETER * 2);
  unsigned short* PET  = (unsigned short*)carve((size_t)HID * EMBD * 2);
  unsigned short* AWT  = (unsigned short*)carve((size_t)HID * 64 * 2);
  unsigned short* ZWB  = (unsigned short*)carve((size_t)STOCH * HID * 2);
  unsigned short* POMB = (unsigned short*)carve((size_t)HID * 128 * 2);
  unsigned short* PRHT = (unsigned short*)carve((size_t)HID * DETER * 2);
  unsigned short* PRMT = (unsigned short*)carve((size_t)128 * HID * 2);
  unsigned short* EAB  = (unsigned short*)carve((size_t)NSTEP * BDIM * HID * 2);  // EA bf16
  unsigned short* XPB  = (unsigned short*)carve((size_t)NSTEP * BDIM * HID * 2);  // prior x bf16
  unsigned short* XABP = (unsigned short*)carve((size_t)NSTEP * BDIM * HID * 2);  // XAB, later PRIN
  unsigned short* HSBF = (unsigned short*)carve((size_t)NSTEP * BDIM * DETER * 2);
  unsigned short* ASTK = (unsigned short*)carve((size_t)BDIM * HID * 2);
  unsigned short* HNB0 = (unsigned short*)carve((size_t)BDIM * DETER * 2);
  unsigned short* HNB1 = (unsigned short*)carve((size_t)BDIM * DETER * 2);
  float*          HF32 = (float*)carve((size_t)BDIM * DETER * 4);
  float*          X2P  = (float*)carve((size_t)4 * BDIM * HID * 4);
  unsigned short* EMBB = HSBF;   // overlay: embed-bf16 lives in HSBF until EA gemm done (pre-loop)

  dim3 tb(32, 8);
  // weight prep
  k_wt_gate<<<dim3(192, 96), tb, 0, stream>>>(gru_wi, gru_wh, WT);
  k_transpose_bf16<<<dim3(32, 64), tb, 0, stream>>>(ph_w, 1024, PHT, DETER);
  k_transpose_bf16<<<dim3(32, 48), tb, 0, stream>>>(pe_w, 1024, PET, EMBD);
  k_transpose_bf16<<<dim3(32, 2), tb, 0, stream>>>(a_w, 1024, AWT, 64);
  k_transpose_bf16<<<dim3(32, 64), tb, 0, stream>>>(prh_w, 1024, PRHT, DETER);
  k_transpose_bf16<<<dim3(4, 32), tb, 0, stream>>>(prm_w, 128, PRMT, HID);
  k_cvt_bf16<<<512, 256, 0, stream>>>(pom_w, POMB, HID * 128);
  k_cvt_bf16<<<256, 256, 0, stream>>>(z_w, ZWB, STOCH * HID);
  k_init_state<<<2048, 256, 0, stream>>>(h0, reset, HF32, HNB0);
  // embed -> bf16 (into HSBF overlay)
  k_cvt4<<<(NSTEP * BDIM * EMBD / 4 + 255) / 256, 256, 0, stream>>>(embed, EMBB, NSTEP * BDIM * EMBD / 4);
  // XAB = action @ a_w + z_b (bf16), all steps
  k_gemm<true, true><<<dim3(16, 200), 256, 0, stream>>>(action, 64, AWT, 64, z_b, XABP, HID, 64);
  // EA = embed @ pe_w (bf16), all steps  (128x64 tiles: 16 n x 100 m = 1600 WG)
  k_gemm2<true><<<1600, 256, 0, stream>>>(EMBB, EMBD, PET, EMBD, nullptr, EAB, HID, EMBD);
  // t=0 input path
  k_pre0<<<BDIM, 256, 0, stream>>>(z0, reset, z_w, XABP, in_g, in_b, ASTK);

  for (int t = 0; t < NSTEP; t++) {
    const unsigned short* hr = (t & 1) ? HNB1 : HNB0;
    unsigned short* hw = (t & 1) ? HNB0 : HNB1;
    k_gru<<<512, 512, 0, stream>>>(t, ASTK, hr, WT, gru_bi, gru_bh, reset,
                                   HF32, hw, HSBF, out);
    k_ph<<<512, 512, 0, stream>>>(t, HSBF, PHT, X2P);
    k_post<<<BDIM, 256, 0, stream>>>(t, X2P, ph_b, EAB, pon_g, pon_b, POMB, pom_b,
                                     noises, reset, ZWB, XABP, in_g, in_b, out, ASTK);
  }

  // batch prior: XP = hs @ prh_w + prh_b (bf16); PRIN overlays XABP
  k_gemm2<true><<<1600, 256, 0, stream>>>(HSBF, DETER, PRHT, DETER, prh_b, XPB, HID, DETER);
  k_ln_elu<<<NSTEP * BDIM, 256, 0, stream>>>(XPB, prn_g, prn_b, XABP);
  k_gemm<false, false><<<dim3(2, 200), 256, 0, stream>>>(XABP, HID, PRMT, HID, prm_b, out, OUTW, HID);
}

// Round 18
// 2477.586 us; speedup vs baseline: 1.1485x; 1.0493x over previous
//
#include <hip/hip_runtime.h>
#include <hip/hip_bf16.h>

typedef __attribute__((ext_vector_type(8))) short short8;
typedef __attribute__((ext_vector_type(4))) short short4v;
typedef __attribute__((ext_vector_type(4))) float floatx4;

#define MFMA16x32(a, b, c) __builtin_amdgcn_mfma_f32_16x16x32_bf16((a), (b), (c), 0, 0, 0)
#define GLDS(gp, lp) __builtin_amdgcn_global_load_lds( \
    (__attribute__((address_space(1))) unsigned int*)(gp), \
    (__attribute__((address_space(3))) unsigned int*)(lp), 16, 0, 0)

#define NSTEP 50
#define BDIM  256
#define EMBD  1536
#define DETER 2048
#define STOCH 64
#define HID   1024
#define OUTW  2368   // 128 priors + 128 posts + 2048 h + 64 z
#define LNEPS 1e-3f

__device__ __forceinline__ unsigned short f2bf(float f) {
  union { float f; unsigned u; } v; v.f = f;
  unsigned r = v.u + 0x7fffu + ((v.u >> 16) & 1u);   // RNE
  return (unsigned short)(r >> 16);
}
__device__ __forceinline__ float bf2f(unsigned short h) {
  union { unsigned u; float f; } v; v.u = (unsigned)h << 16;
  return v.f;
}
__device__ __forceinline__ float sgm(float x) { return 1.f / (1.f + __expf(-x)); }
__device__ __forceinline__ float elu1(float x) { return x > 0.f ? x : expm1f(x); }

__device__ __forceinline__ void block_sum2(float& s, float& q, float* red, int tid) {
  #pragma unroll
  for (int m = 1; m < 64; m <<= 1) { s += __shfl_xor(s, m, 64); q += __shfl_xor(q, m, 64); }
  int w = tid >> 6;
  if ((tid & 63) == 0) { red[w * 2] = s; red[w * 2 + 1] = q; }
  __syncthreads();
  s = red[0] + red[2] + red[4] + red[6];
  q = red[1] + red[3] + red[5] + red[7];
}

// 8-wave (512-thread) version; red must hold >=16 floats; ALL threads execute.
__device__ __forceinline__ void block_sum2_8w(float& s, float& q, float* red, int tid) {
  #pragma unroll
  for (int m = 1; m < 64; m <<= 1) { s += __shfl_xor(s, m, 64); q += __shfl_xor(q, m, 64); }
  int w = tid >> 6;
  if ((tid & 63) == 0) { red[w * 2] = s; red[w * 2 + 1] = q; }
  __syncthreads();
  s = red[0] + red[2] + red[4] + red[6] + red[8] + red[10] + red[12] + red[14];
  q = red[1] + red[3] + red[5] + red[7] + red[9] + red[11] + red[13] + red[15];
}

// ---------------- weight prep ----------------
__global__ void k_transpose_bf16(const float* __restrict__ src, int N,
                                 unsigned short* __restrict__ dst, int ldd) {
  __shared__ float tile[32][33];
  int n0 = blockIdx.x * 32, k0 = blockIdx.y * 32;
  for (int i = threadIdx.y; i < 32; i += 8)
    tile[i][threadIdx.x] = src[(size_t)(k0 + i) * N + n0 + threadIdx.x];
  __syncthreads();
  for (int i = threadIdx.y; i < 32; i += 8)
    dst[(size_t)(n0 + i) * ldd + k0 + threadIdx.x] = f2bf(tile[threadIdx.x][i]);
}

// WT gate-interleaved: out row rr: j=(rr/48)*16+(rr&15), g=(rr%48)>>4, src col=g*2048+j
__global__ void k_wt_gate(const float* __restrict__ wi, const float* __restrict__ wh,
                          unsigned short* __restrict__ dst) {
  __shared__ float tile[32][33];
  int r0 = blockIdx.x * 32, k0 = blockIdx.y * 32;
  int rr = r0 + threadIdx.x;
  int j = (rr / 48) * 16 + (rr & 15), g = (rr % 48) >> 4;
  int c = g * 2048 + j;
  for (int i = threadIdx.y; i < 32; i += 8) {
    int k = k0 + i;
    tile[i][threadIdx.x] = (k < 1024) ? wi[(size_t)k * 6144 + c]
                                      : wh[(size_t)(k - 1024) * 6144 + c];
  }
  __syncthreads();
  for (int i = threadIdx.y; i < 32; i += 8)
    dst[(size_t)(r0 + i) * 3072 + k0 + threadIdx.x] = f2bf(tile[threadIdx.x][i]);
}

__global__ void k_cvt_bf16(const float* __restrict__ src, unsigned short* __restrict__ dst, int n) {
  int i = blockIdx.x * blockDim.x + threadIdx.x;
  if (i < n) dst[i] = f2bf(src[i]);
}

__global__ void k_cvt4(const float* __restrict__ src, unsigned short* __restrict__ dst, int n4) {
  int i = blockIdx.x * 256 + threadIdx.x;
  if (i < n4) {
    floatx4 v = ((const floatx4*)src)[i];
    short4v o;
    #pragma unroll
    for (int j = 0; j < 4; j++) o[j] = (short)f2bf(v[j]);
    ((short4v*)dst)[i] = o;
  }
}

__global__ void k_init_state(const float* __restrict__ h0, const unsigned char* __restrict__ reset,
                             float* __restrict__ h_f32, unsigned short* __restrict__ hnb0) {
  int i = blockIdx.x * 256 + threadIdx.x;
  if (i < BDIM * DETER) {
    float m = reset[i >> 11] ? 0.f : 1.f;
    float v = h0[i] * m;
    h_f32[i] = v;
    hnb0[i] = f2bf(v);
  }
}

// ---------------- old-style 64x64 gemm (XAB K=64 f32-A; final prior head) ----------------
template <bool AF32, bool C16>
__global__ __launch_bounds__(256) void k_gemm(
    const void* __restrict__ Ap, long lda,
    const unsigned short* __restrict__ Bt, long ldb,
    const float* __restrict__ bias,
    void* __restrict__ Cp, long ldc, int K) {
  __shared__ __attribute__((aligned(16))) short A_s[64][72];
  __shared__ __attribute__((aligned(16))) short B_s[64][72];
  int n0 = blockIdx.x * 64, m0 = blockIdx.y * 64;
  int tid = threadIdx.x, wave = tid >> 6, lane = tid & 63;
  int srow = tid >> 3, skk = (tid & 7) * 8;
  int fr = lane & 15, fq = lane >> 4;
  int mb = (wave & 1) * 32, nb = (wave >> 1) * 32;
  const unsigned short* a16 = (const unsigned short*)Ap;
  const float* a32 = (const float*)Ap;
  floatx4 acc[2][2] = {};
  for (int k0 = 0; k0 < K; k0 += 64) {
    short8 av0, av1, bv0, bv1;
    if constexpr (AF32) {
      floatx4 f0 = *(const floatx4*)(a32 + (size_t)(m0 + srow) * lda + k0 + skk);
      floatx4 f1 = *(const floatx4*)(a32 + (size_t)(m0 + srow) * lda + k0 + skk + 4);
      floatx4 f2 = *(const floatx4*)(a32 + (size_t)(m0 + srow + 32) * lda + k0 + skk);
      floatx4 f3 = *(const floatx4*)(a32 + (size_t)(m0 + srow + 32) * lda + k0 + skk + 4);
      #pragma unroll
      for (int i = 0; i < 4; i++) {
        av0[i] = (short)f2bf(f0[i]); av0[4 + i] = (short)f2bf(f1[i]);
        av1[i] = (short)f2bf(f2[i]); av1[4 + i] = (short)f2bf(f3[i]);
      }
    } else {
      av0 = *(const short8*)(a16 + (size_t)(m0 + srow) * lda + k0 + skk);
      av1 = *(const short8*)(a16 + (size_t)(m0 + srow + 32) * lda + k0 + skk);
    }
    bv0 = *(const short8*)(Bt + (size_t)(n0 + srow) * ldb + k0 + skk);
    bv1 = *(const short8*)(Bt + (size_t)(n0 + srow + 32) * ldb + k0 + skk);
    __syncthreads();
    *(short8*)&A_s[srow][skk] = av0;
    *(short8*)&A_s[32 + srow][skk] = av1;
    *(short8*)&B_s[srow][skk] = bv0;
    *(short8*)&B_s[32 + srow][skk] = bv1;
    __syncthreads();
    #pragma unroll
    for (int ks = 0; ks < 2; ks++) {
      short8 a0 = *(const short8*)&A_s[mb + fr][ks * 32 + fq * 8];
      short8 a1 = *(const short8*)&A_s[mb + 16 + fr][ks * 32 + fq * 8];
      short8 b0 = *(const short8*)&B_s[nb + fr][ks * 32 + fq * 8];
      short8 b1 = *(const short8*)&B_s[nb + 16 + fr][ks * 32 + fq * 8];
      acc[0][0] = MFMA16x32(a0, b0, acc[0][0]);
      acc[0][1] = MFMA16x32(a0, b1, acc[0][1]);
      acc[1][0] = MFMA16x32(a1, b0, acc[1][0]);
      acc[1][1] = MFMA16x32(a1, b1, acc[1][1]);
    }
  }
  #pragma unroll
  for (int mi = 0; mi < 2; mi++)
    #pragma unroll
    for (int ni = 0; ni < 2; ni++)
      #pragma unroll
      for (int j = 0; j < 4; j++) {
        int row = m0 + mb + mi * 16 + fq * 4 + j;
        int col = n0 + nb + ni * 16 + fr;
        float v = acc[mi][ni][j];
        if (bias) v += bias[col];
        if constexpr (C16) ((unsigned short*)Cp)[(size_t)row * ldc + col] = f2bf(v);
        else               ((float*)Cp)[(size_t)row * ldc + col] = v;
      }
}

// ---------------- 128x64 GLDS+swizzle batch gemm, XCD-chunked, counted-vmcnt (round-15) ----------------
template <bool C16>
__global__ __launch_bounds__(256) void k_gemm2(
    const unsigned short* __restrict__ A, long lda,
    const unsigned short* __restrict__ Bt, long ldb,
    const float* __restrict__ bias,
    void* __restrict__ Cp, long ldc, int K) {
  __shared__ __attribute__((aligned(1024))) unsigned short lds[2][192 * 64];
  int per = gridDim.x >> 3;
  int flat = (blockIdx.x & 7) * per + (blockIdx.x >> 3);  // XCD-chunked bijection
  int n0 = (flat & 15) * 64, m0 = (flat >> 4) * 128;
  int tid = threadIdx.x, w = tid >> 6, lane = tid & 63;
  int lr = lane >> 3, ce = ((lane & 7) ^ lr) << 3;
  int fr = lane & 15, fq = lane >> 4;
  int xr = (fr & 7) << 3;
  int wm = (w & 1) * 64, wn = (w >> 1) * 32;
  auto stage = [&](int buf, int k0) {
    #pragma unroll
    for (int q = 0; q < 6; q++) {
      int j = w * 6 + q;
      int rr = j * 8 + lr;
      const unsigned short* src = (rr < 128)
        ? A + (size_t)(m0 + rr) * lda + k0 + ce
        : Bt + (size_t)(n0 + rr - 128) * ldb + k0 + ce;
      GLDS(src, &lds[buf][j * 512]);
    }
  };
  floatx4 acc[4][2] = {};
  int niter = K / 64;
  stage(0, 0); stage(1, 64);
  for (int ks = 0; ks < niter; ks++) {
    int cur = ks & 1;
    if (ks + 1 < niter) asm volatile("s_waitcnt vmcnt(6)" ::: "memory");
    else                asm volatile("s_waitcnt vmcnt(0)" ::: "memory");
    __builtin_amdgcn_s_barrier();
    __builtin_amdgcn_sched_barrier(0);
    const unsigned short* L = lds[cur];
    __builtin_amdgcn_s_setprio(1);
    #pragma unroll
    for (int kh = 0; kh < 2; kh++) {
      int kb = kh * 32 + fq * 8;
      short8 af[4], bf[2];
      #pragma unroll
      for (int i = 0; i < 4; i++)
        af[i] = *(const short8*)&L[((wm + i * 16 + fr) * 64 + kb) ^ xr];
      #pragma unroll
      for (int i = 0; i < 2; i++)
        bf[i] = *(const short8*)&L[((128 + wn + i * 16 + fr) * 64 + kb) ^ xr];
      #pragma unroll
      for (int mi = 0; mi < 4; mi++)
        #pragma unroll
        for (int ni = 0; ni < 2; ni++)
          acc[mi][ni] = MFMA16x32(af[mi], bf[ni], acc[mi][ni]);
    }
    __builtin_amdgcn_s_setprio(0);
    __builtin_amdgcn_sched_barrier(0);
    __builtin_amdgcn_s_barrier();
    if (ks + 2 < niter) stage(cur, (ks + 2) * 64);
  }
  #pragma unroll
  for (int mi = 0; mi < 4; mi++)
    #pragma unroll
    for (int ni = 0; ni < 2; ni++)
      #pragma unroll
      for (int j = 0; j < 4; j++) {
        int row = m0 + wm + mi * 16 + fq * 4 + j;
        int col = n0 + wn + ni * 16 + fr;
        float v = acc[mi][ni][j];
        if (bias) v += bias[col];
        if constexpr (C16) ((unsigned short*)Cp)[(size_t)row * ldc + col] = f2bf(v);
        else               ((float*)Cp)[(size_t)row * ldc + col] = v;
      }
}

// ---------------- per-step k_gru: BM=32, 512 threads, grid 512 (round-16 passing) ----------------
__global__ __launch_bounds__(512) void k_gru(
    int t, const unsigned short* __restrict__ astk, const unsigned short* __restrict__ hnb_r,
    const unsigned short* __restrict__ wt,
    const float* __restrict__ gbi, const float* __restrict__ gbh,
    const unsigned char* __restrict__ reset,
    float* __restrict__ h_f32, unsigned short* __restrict__ hnb_w,
    unsigned short* __restrict__ hs_bf, float* __restrict__ out) {
  __shared__ __attribute__((aligned(1024))) unsigned short lds[2][128 * 64];
  int raw = blockIdx.x;
  int xcd = raw & 7, ii = raw >> 3;              // ii 0..63
  int n_t = xcd * 8 + (ii & 7), m_t = ii >> 3;   // n_t 0..63, m_t 0..7
  int m0 = m_t * 32;
  int tid = threadIdx.x, w = tid >> 6, lane = tid & 63;
  int lr = lane >> 3;
  int ce = ((lane & 7) ^ lr) << 3;       // pre-swizzled source col (elem units)
  int fr = lane & 15, fq = lane >> 4;
  int xr = (fr & 7) << 3;                // read-side XOR (short units)
  int rh = w & 1, wc = (w >> 1) & 1, kh = w >> 2;

  auto stage = [&](int buf, int k0) {
    #pragma unroll
    for (int q = 0; q < 2; q++) {
      int j = w * 2 + q;                 // j 0..15 -> rows 0..127
      int rr = j * 8 + lr;
      const unsigned short* src;
      if (rr < 32) {
        src = (k0 < HID) ? astk + (size_t)(m0 + rr) * HID + (k0 + ce)
                         : hnb_r + (size_t)(m0 + rr) * DETER + (k0 - HID + ce);
      } else {
        src = wt + (size_t)(n_t * 96 + rr - 32) * 3072 + (k0 + ce);
      }
      GLDS(src, &lds[buf][j * 512]);
    }
  };

  floatx4 acc[4] = {};   // r,u,ic,hc -- this wave's (rh,wc,kh) role
  stage(0, 0); stage(1, 64);
  for (int ks = 0; ks < 48; ks++) {
    int cur = ks & 1;
    if (ks < 47) asm volatile("s_waitcnt vmcnt(2)" ::: "memory");
    else         asm volatile("s_waitcnt vmcnt(0)" ::: "memory");
    __builtin_amdgcn_s_barrier();
    __builtin_amdgcn_sched_barrier(0);
    const unsigned short* L = lds[cur];
    __builtin_amdgcn_s_setprio(1);
    {
      int kb = kh * 32 + fq * 8;
      short8 a0 = *(const short8*)&L[((rh * 16 + fr) * 64 + kb) ^ xr];
      short8 br = *(const short8*)&L[((32 + wc * 48 + fr) * 64 + kb) ^ xr];
      short8 bu = *(const short8*)&L[((32 + wc * 48 + 16 + fr) * 64 + kb) ^ xr];
      short8 bc = *(const short8*)&L[((32 + wc * 48 + 32 + fr) * 64 + kb) ^ xr];
      acc[0] = MFMA16x32(a0, br, acc[0]);
      acc[1] = MFMA16x32(a0, bu, acc[1]);
      if (ks < 16) acc[2] = MFMA16x32(a0, bc, acc[2]);
      else         acc[3] = MFMA16x32(a0, bc, acc[3]);
    }
    __builtin_amdgcn_s_setprio(0);
    __builtin_amdgcn_sched_barrier(0);
    __builtin_amdgcn_s_barrier();
    if (ks + 2 < 48) stage(cur, (ks + 2) * 64);
  }
  // cross-wave kh reduction: waves 4..7 -> waves 0..3 (same rh,wc role). 16KB scratch.
  __syncthreads();
  float* red = (float*)lds;
  if (kh == 1) {
    int base = ((w - 4) * 64 + lane) * 16;
    #pragma unroll
    for (int g = 0; g < 4; g++)
      *(floatx4*)&red[base + g * 4] = acc[g];
  }
  __syncthreads();
  if (kh == 0) {
    int base = (w * 64 + lane) * 16;
    #pragma unroll
    for (int g = 0; g < 4; g++)
      acc[g] += *(const floatx4*)&red[base + g * 4];
    int jc = n_t * 32 + wc * 16 + fr;
    float bir = gbi[jc],        bhr = gbh[jc];
    float biu = gbi[jc + 2048], bhu = gbh[jc + 2048];
    float bic = gbi[jc + 4096], bhc = gbh[jc + 4096];
    #pragma unroll
    for (int j = 0; j < 4; j++) {
      int b = m0 + rh * 16 + fq * 4 + j;
      float r = sgm(acc[0][j] + bir + bhr);
      float u = sgm(acc[1][j] + biu + bhu);
      float c = tanhf(acc[2][j] + bic + r * (acc[3][j] + bhc));
      size_t hi = (size_t)b * DETER + jc;
      float hold = h_f32[hi];
      float hn = (1.f - u) * c + u * hold;
      out[((size_t)t * BDIM + b) * OUTW + 256 + jc] = hn;
      hs_bf[((size_t)t * BDIM + b) * DETER + jc] = f2bf(hn);
      float mn = (t + 1 < NSTEP && reset[(size_t)(t + 1) * BDIM + b]) ? 0.f : 1.f;
      float hm = hn * mn;
      h_f32[hi] = hm;
      hnb_w[hi] = f2bf(hm);
    }
  }
}

// ---------------- per-step k_ph: 512 threads, split-K=4, grid 512 (round-17 passing) ----------------
__global__ __launch_bounds__(512) void k_ph(
    int t, const unsigned short* __restrict__ hsbf, const unsigned short* __restrict__ pht,
    float* __restrict__ x2p) {
  __shared__ __attribute__((aligned(1024))) unsigned short lds[2][128 * 64];
  int raw = blockIdx.x;
  int n_t = raw & 15, m_t = (raw >> 4) & 7, kslc = raw >> 7;
  int m0 = m_t * 32, n0 = n_t * 64, koff = kslc * 512;
  const unsigned short* hb = hsbf + (size_t)t * BDIM * DETER;
  int tid = threadIdx.x, w = tid >> 6, lane = tid & 63;
  int lr = lane >> 3;
  int ce = ((lane & 7) ^ lr) << 3;
  int fr = lane & 15, fq = lane >> 4;
  int xr = (fr & 7) << 3;
  int wc = w & 3, kh = w >> 2;

  auto stage = [&](int buf, int k0) {
    #pragma unroll
    for (int q = 0; q < 2; q++) {
      int j = w * 2 + q;                 // j 0..15 -> rows 0..127
      int rr = j * 8 + lr;
      const unsigned short* src;
      if (rr < 32) {
        src = hb + (size_t)(m0 + rr) * DETER + koff + k0 + ce;
      } else {
        int brow = rr - 32;
        if (brow > 63) brow = 63;        // pad rows: harmless duplicate load
        src = pht + (size_t)(n0 + brow) * DETER + koff + k0 + ce;
      }
      GLDS(src, &lds[buf][j * 512]);
    }
  };

  floatx4 acc[2] = {};
  stage(0, 0); stage(1, 64);
  for (int ks = 0; ks < 8; ks++) {
    int cur = ks & 1;
    if (ks < 7) asm volatile("s_waitcnt vmcnt(2)" ::: "memory");
    else        asm volatile("s_waitcnt vmcnt(0)" ::: "memory");
    __builtin_amdgcn_s_barrier();
    __builtin_amdgcn_sched_barrier(0);
    const unsigned short* L = lds[cur];
    __builtin_amdgcn_s_setprio(1);
    {
      int kb = kh * 32 + fq * 8;
      short8 a0 = *(const short8*)&L[((fr) * 64 + kb) ^ xr];
      short8 a1 = *(const short8*)&L[((16 + fr) * 64 + kb) ^ xr];
      short8 bw = *(const short8*)&L[((32 + wc * 16 + fr) * 64 + kb) ^ xr];
      acc[0] = MFMA16x32(a0, bw, acc[0]);
      acc[1] = MFMA16x32(a1, bw, acc[1]);
    }
    __builtin_amdgcn_s_setprio(0);
    __builtin_amdgcn_sched_barrier(0);
    __builtin_amdgcn_s_barrier();
    if (ks + 2 < 8) stage(cur, (ks + 2) * 64);
  }
  // kh reduction: waves 4..7 -> 0..3
  __syncthreads();
  float* red = (float*)lds;
  if (kh == 1) {
    int p = w - 4;
    #pragma unroll
    for (int g = 0; g < 2; g++)
      *(floatx4*)&red[((g * 4 + p) * 64 + lane) * 4] = acc[g];
  }
  __syncthreads();
  if (kh == 0) {
    int p = w;
    #pragma unroll
    for (int g = 0; g < 2; g++)
      acc[g] += *(const floatx4*)&red[((g * 4 + p) * 64 + lane) * 4];
    int col = n0 + wc * 16 + fr;
    #pragma unroll
    for (int mi = 0; mi < 2; mi++)
      #pragma unroll
      for (int j = 0; j < 4; j++)
        x2p[(size_t)(kslc * BDIM + m0 + mi * 16 + fq * 4 + j) * HID + col] = acc[mi][j];
  }
}

// ---------------- per-step k_post: 512 threads (2 waves/SIMD), 4 x2p partials ----------------
__global__ __launch_bounds__(512) void k_post(
    int t, const float* __restrict__ x2p, const float* __restrict__ ph_b,
    const unsigned short* __restrict__ eab,
    const float* __restrict__ pon_g, const float* __restrict__ pon_b,
    const unsigned short* __restrict__ pomb, const float* __restrict__ pom_b,
    const float* __restrict__ noises, const unsigned char* __restrict__ reset,
    const unsigned short* __restrict__ zwb, const unsigned short* __restrict__ xab,
    const float* __restrict__ in_g, const float* __restrict__ in_b,
    float* __restrict__ out, unsigned short* __restrict__ astk) {
  int b = blockIdx.x, tid = threadIdx.x;   // 512 threads
  __shared__ float pin[HID];
  __shared__ float red[16];
  __shared__ float post[128];
  __shared__ float zm[64];
  __shared__ float pacc[512];
  int j0 = tid * 2;                        // 2 cols per thread
  float x0 = x2p[(size_t)b * HID + j0];
  float x1 = x2p[(size_t)b * HID + j0 + 1];
  #pragma unroll
  for (int p = 1; p < 4; p++) {
    x0 += x2p[(size_t)(p * BDIM + b) * HID + j0];
    x1 += x2p[(size_t)(p * BDIM + b) * HID + j0 + 1];
  }
  unsigned e2 = *(const unsigned*)&eab[((size_t)t * BDIM + b) * HID + j0];
  x0 += ph_b[j0]     + bf2f((unsigned short)(e2 & 0xffffu));
  x1 += ph_b[j0 + 1] + bf2f((unsigned short)(e2 >> 16));
  float s = x0 + x1;
  float q = x0 * x0 + x1 * x1;
  block_sum2_8w(s, q, red, tid);
  float mean = s * (1.f / HID);
  float rstd = rsqrtf(q * (1.f / HID) - mean * mean + LNEPS);
  pin[j0]     = elu1((x0 - mean) * rstd * pon_g[j0]     + pon_b[j0]);
  pin[j0 + 1] = elu1((x1 - mean) * rstd * pon_g[j0 + 1] + pon_b[j0 + 1]);
  __syncthreads();
  {
    int col = tid & 127, qtr = tid >> 7;   // 4-way K split of 256 each
    const unsigned short* pb = pomb + (size_t)(qtr * 256) * 128 + col;
    const float* pi = pin + qtr * 256;
    float a0 = 0, a1 = 0, a2 = 0, a3 = 0;
    #pragma unroll 8
    for (int k = 0; k < 256; k += 4) {
      a0 += pi[k]     * bf2f(pb[(size_t)k * 128]);
      a1 += pi[k + 1] * bf2f(pb[(size_t)(k + 1) * 128]);
      a2 += pi[k + 2] * bf2f(pb[(size_t)(k + 2) * 128]);
      a3 += pi[k + 3] * bf2f(pb[(size_t)(k + 3) * 128]);
    }
    pacc[tid] = (a0 + a1) + (a2 + a3);
  }
  __syncthreads();
  size_t ro = ((size_t)t * BDIM + b) * OUTW;
  if (tid < 128) {
    float p = pacc[tid] + pacc[tid + 128] + pacc[tid + 256] + pacc[tid + 384] + pom_b[tid];
    post[tid] = p;
    out[ro + 128 + tid] = p;
  }
  __syncthreads();
  if (tid < 64) {
    float mn = post[tid], raw = post[64 + tid];
    float std = 2.f * sgm(raw) + 0.1f;
    float z = mn + std * noises[((size_t)t * BDIM + b) * STOCH + tid];
    out[ro + 2304 + tid] = z;
    float mk = (t + 1 < NSTEP && reset[(size_t)(t + 1) * BDIM + b]) ? 0.f : 1.f;
    zm[tid] = z * mk;
  }
  __syncthreads();
  if (t + 1 < NSTEP) {
    unsigned xa2 = *(const unsigned*)&xab[((size_t)(t + 1) * BDIM + b) * HID + j0];
    float xn0 = bf2f((unsigned short)(xa2 & 0xffffu));
    float xn1 = bf2f((unsigned short)(xa2 >> 16));
    #pragma unroll 8
    for (int k = 0; k < 64; k++) {
      unsigned wv = *(const unsigned*)&zwb[(size_t)k * HID + j0];
      float zk = zm[k];
      xn0 += zk * bf2f((unsigned short)(wv & 0xffffu));
      xn1 += zk * bf2f((unsigned short)(wv >> 16));
    }
    float s2 = xn0 + xn1;
    float q2 = xn0 * xn0 + xn1 * xn1;
    block_sum2_8w(s2, q2, red, tid);
    float mean2 = s2 * (1.f / HID);
    float rstd2 = rsqrtf(q2 * (1.f / HID) - mean2 * mean2 + LNEPS);
    unsigned short o0 = f2bf(elu1((xn0 - mean2) * rstd2 * in_g[j0]     + in_b[j0]));
    unsigned short o1 = f2bf(elu1((xn1 - mean2) * rstd2 * in_g[j0 + 1] + in_b[j0 + 1]));
    *(unsigned*)&astk[(size_t)b * HID + j0] = (unsigned)o0 | ((unsigned)o1 << 16);
  }
}

// ---------------- t=0 input path ----------------
__global__ __launch_bounds__(256) void k_pre0(
    const float* __restrict__ z0, const unsigned char* __restrict__ reset,
    const float* __restrict__ z_w, const unsigned short* __restrict__ xab,
    const float* __restrict__ in_g, const float* __restrict__ in_b,
    unsigned short* __restrict__ astk) {
  int b = blockIdx.x, tid = threadIdx.x;
  __shared__ float zm[64];
  __shared__ float red[8];
  if (tid < 64) {
    float mk = reset[b] ? 0.f : 1.f;
    zm[tid] = z0[(size_t)b * STOCH + tid] * mk;
  }
  __syncthreads();
  int j0 = tid * 4;
  short4v xa = *(const short4v*)&xab[(size_t)b * HID + j0];
  floatx4 xn;
  #pragma unroll
  for (int i = 0; i < 4; i++) xn[i] = bf2f((unsigned short)xa[i]);
  #pragma unroll 8
  for (int k = 0; k < 64; k++) {
    floatx4 wv = *(const floatx4*)&z_w[(size_t)k * HID + j0];
    xn += zm[k] * wv;
  }
  float s = xn[0] + xn[1] + xn[2] + xn[3];
  float q = xn[0]*xn[0] + xn[1]*xn[1] + xn[2]*xn[2] + xn[3]*xn[3];
  block_sum2(s, q, red, tid);
  float mean = s * (1.f / HID);
  float rstd = rsqrtf(q * (1.f / HID) - mean * mean + LNEPS);
  short4v ov;
  #pragma unroll
  for (int i = 0; i < 4; i++)
    ov[i] = (short)f2bf(elu1((xn[i] - mean) * rstd * in_g[j0 + i] + in_b[j0 + i]));
  *(short4v*)&astk[(size_t)b * HID + j0] = ov;
}

// ---------------- batch LN+ELU (prior path, bf16 in/out) ----------------
__global__ __launch_bounds__(256) void k_ln_elu(
    const unsigned short* __restrict__ X, const float* __restrict__ g, const float* __restrict__ bb,
    unsigned short* __restrict__ Y) {
  int row = blockIdx.x, tid = threadIdx.x;
  __shared__ float red[8];
  int j0 = tid * 4;
  short4v v4 = *(const short4v*)&X[(size_t)row * HID + j0];
  floatx4 v;
  #pragma unroll
  for (int i = 0; i < 4; i++) v[i] = bf2f((unsigned short)v4[i]);
  float s = v[0] + v[1] + v[2] + v[3];
  float q = v[0]*v[0] + v[1]*v[1] + v[2]*v[2] + v[3]*v[3];
  block_sum2(s, q, red, tid);
  float mean = s * (1.f / HID);
  float rstd = rsqrtf(q * (1.f / HID) - mean * mean + LNEPS);
  short4v ov;
  #pragma unroll
  for (int i = 0; i < 4; i++)
    ov[i] = (short)f2bf(elu1((v[i] - mean) * rstd * g[j0 + i] + bb[j0 + i]));
  *(short4v*)&Y[(size_t)row * HID + j0] = ov;
}

extern "C" void kernel_launch(void* const* d_in, const int* in_sizes, int n_in,
                              void* d_out, int out_size, void* d_ws, size_t ws_size,
                              hipStream_t stream) {
  (void)in_sizes; (void)n_in; (void)out_size; (void)ws_size;
  const float* embed  = (const float*)d_in[0];
  const float* action = (const float*)d_in[1];
  const unsigned char* reset = (const unsigned char*)d_in[2];
  const float* h0     = (const float*)d_in[3];
  const float* z0     = (const float*)d_in[4];
  const float* noises = (const float*)d_in[5];
  const float* z_w    = (const float*)d_in[6];
  const float* z_b    = (const float*)d_in[7];
  const float* a_w    = (const float*)d_in[8];
  const float* in_g   = (const float*)d_in[9];
  const float* in_b   = (const float*)d_in[10];
  const float* gru_wi = (const float*)d_in[11];
  const float* gru_wh = (const float*)d_in[12];
  const float* gru_bi = (const float*)d_in[13];
  const float* gru_bh = (const float*)d_in[14];
  const float* ph_w   = (const float*)d_in[15];
  const float* ph_b   = (const float*)d_in[16];
  const float* pe_w   = (const float*)d_in[17];
  const float* pon_g  = (const float*)d_in[18];
  const float* pon_b  = (const float*)d_in[19];
  const float* pom_w  = (const float*)d_in[20];
  const float* pom_b  = (const float*)d_in[21];
  const float* prh_w  = (const float*)d_in[22];
  const float* prh_b  = (const float*)d_in[23];
  const float* prn_g  = (const float*)d_in[24];
  const float* prn_b  = (const float*)d_in[25];
  const float* prm_w  = (const float*)d_in[26];
  const float* prm_b  = (const float*)d_in[27];
  float* out = (float*)d_out;

  // ---- workspace carve (~186 MB) ----
  char* w = (char*)d_ws;
  auto carve = [&](size_t bytes) { char* p = w; w += (bytes + 255) & ~(size_t)255; return p; };
  unsigned short* WT   = (unsigned short*)carve((size_t)6144 * 3072 * 2);
  unsigned short* PHT  = (unsigned short*)carve((size_t)HID * DETER * 2);
  unsigned short* PET  = (unsigned short*)carve((size_t)HID * EMBD * 2);
  unsigned short* AWT  = (unsigned short*)carve((size_t)HID * 64 * 2);
  unsigned short* ZWB  = (unsigned short*)carve((size_t)STOCH * HID * 2);
  unsigned short* POMB = (unsigned short*)carve((size_t)HID * 128 * 2);
  unsigned short* PRHT = (unsigned short*)carve((size_t)HID * DETER * 2);
  unsigned short* PRMT = (unsigned short*)carve((size_t)128 * HID * 2);
  unsigned short* EAB  = (unsigned short*)carve((size_t)NSTEP * BDIM * HID * 2);  // EA bf16
  unsigned short* XPB  = (unsigned short*)carve((size_t)NSTEP * BDIM * HID * 2);  // prior x bf16
  unsigned short* XABP = (unsigned short*)carve((size_t)NSTEP * BDIM * HID * 2);  // XAB, later PRIN
  unsigned short* HSBF = (unsigned short*)carve((size_t)NSTEP * BDIM * DETER * 2);
  unsigned short* ASTK = (unsigned short*)carve((size_t)BDIM * HID * 2);
  unsigned short* HNB0 = (unsigned short*)carve((size_t)BDIM * DETER * 2);
  unsigned short* HNB1 = (unsigned short*)carve((size_t)BDIM * DETER * 2);
  float*          HF32 = (float*)carve((size_t)BDIM * DETER * 4);
  float*          X2P  = (float*)carve((size_t)4 * BDIM * HID * 4);
  unsigned short* EMBB = HSBF;   // overlay: embed-bf16 lives in HSBF until EA gemm done (pre-loop)

  dim3 tb(32, 8);
  // weight prep
  k_wt_gate<<<dim3(192, 96), tb, 0, stream>>>(gru_wi, gru_wh, WT);
  k_transpose_bf16<<<dim3(32, 64), tb, 0, stream>>>(ph_w, 1024, PHT, DETER);
  k_transpose_bf16<<<dim3(32, 48), tb, 0, stream>>>(pe_w, 1024, PET, EMBD);
  k_transpose_bf16<<<dim3(32, 2), tb, 0, stream>>>(a_w, 1024, AWT, 64);
  k_transpose_bf16<<<dim3(32, 64), tb, 0, stream>>>(prh_w, 1024, PRHT, DETER);
  k_transpose_bf16<<<dim3(4, 32), tb, 0, stream>>>(prm_w, 128, PRMT, HID);
  k_cvt_bf16<<<512, 256, 0, stream>>>(pom_w, POMB, HID * 128);
  k_cvt_bf16<<<256, 256, 0, stream>>>(z_w, ZWB, STOCH * HID);
  k_init_state<<<2048, 256, 0, stream>>>(h0, reset, HF32, HNB0);
  // embed -> bf16 (into HSBF overlay)
  k_cvt4<<<(NSTEP * BDIM * EMBD / 4 + 255) / 256, 256, 0, stream>>>(embed, EMBB, NSTEP * BDIM * EMBD / 4);
  // XAB = action @ a_w + z_b (bf16), all steps
  k_gemm<true, true><<<dim3(16, 200), 256, 0, stream>>>(action, 64, AWT, 64, z_b, XABP, HID, 64);
  // EA = embed @ pe_w (bf16), all steps  (128x64 tiles: 16 n x 100 m = 1600 WG)
  k_gemm2<true><<<1600, 256, 0, stream>>>(EMBB, EMBD, PET, EMBD, nullptr, EAB, HID, EMBD);
  // t=0 input path
  k_pre0<<<BDIM, 256, 0, stream>>>(z0, reset, z_w, XABP, in_g, in_b, ASTK);

  for (int t = 0; t < NSTEP; t++) {
    const unsigned short* hr = (t & 1) ? HNB1 : HNB0;
    unsigned short* hw = (t & 1) ? HNB0 : HNB1;
    k_gru<<<512, 512, 0, stream>>>(t, ASTK, hr, WT, gru_bi, gru_bh, reset,
                                   HF32, hw, HSBF, out);
    k_ph<<<512, 512, 0, stream>>>(t, HSBF, PHT, X2P);
    k_post<<<BDIM, 512, 0, stream>>>(t, X2P, ph_b, EAB, pon_g, pon_b, POMB, pom_b,
                                     noises, reset, ZWB, XABP, in_g, in_b, out, ASTK);
  }

  // batch prior: XP = hs @ prh_w + prh_b (bf16); PRIN overlays XABP
  k_gemm2<true><<<1600, 256, 0, stream>>>(HSBF, DETER, PRHT, DETER, prh_b, XPB, HID, DETER);
  k_ln_elu<<<NSTEP * BDIM, 256, 0, stream>>>(XPB, prn_g, prn_b, XABP);
  k_gemm<false, false><<<dim3(2, 200), 256, 0, stream>>>(XABP, HID, PRMT, HID, prm_b, out, OUTW, HID);
}